// Round 1
// baseline (3157.720 us; speedup 1.0000x reference)
//
#include <hip/hip_runtime.h>
#include <hip/hip_bf16.h>
#include <math.h>

#define NHEAD 8
#define DKDIM 32

__device__ __forceinline__ void atomicMaxFloat(float* addr, float val) {
    if (val >= 0.0f) atomicMax((int*)addr, __float_as_int(val));
    else atomicMin((unsigned int*)addr, __float_as_uint(val));
}

__global__ void fill_kernel(float* __restrict__ p, float v, int n) {
    int i = blockIdx.x * blockDim.x + threadIdx.x;
    if (i < n) p[i] = v;
}

// C[M,N] = a_scale*(A[M,K] @ W[K,N]) + bias[N]
// blend: C = alpha*that + (1-alpha)*Hprev, alpha = sigmoid(*skipv). In-place safe (C==Hprev).
__global__ __launch_bounds__(256)
void gemm_kernel(const float* __restrict__ A, const float* __restrict__ W,
                 const float* __restrict__ bias, float* __restrict__ C,
                 const float* __restrict__ Hprev, const float* __restrict__ skipv,
                 int M, int N, int K, float a_scale, int blend)
{
    __shared__ float As[16][65];   // [k][m], padded: conflict-free transpose write
    __shared__ float Bs[16][64];   // [k][n]
    const int bm = blockIdx.x * 64;
    const int bn = blockIdx.y * 64;
    const int tid = threadIdx.x;
    const int tx = tid & 15;       // n direction
    const int ty = tid >> 4;       // m direction
    float acc[4][4] = {};

    for (int k0 = 0; k0 < K; k0 += 16) {
        // load A tile 64x16 (row-major in A, transposed into As[k][m])
        #pragma unroll
        for (int it = 0; it < 4; ++it) {
            int i = tid + it * 256;
            int m = i >> 4, kk = i & 15;
            int gm = bm + m;
            As[kk][m] = (gm < M) ? A[(size_t)gm * K + k0 + kk] : 0.0f;
        }
        // load B tile 16x64
        #pragma unroll
        for (int it = 0; it < 4; ++it) {
            int i = tid + it * 256;
            int kk = i >> 6, n = i & 63;
            Bs[kk][n] = W[(size_t)(k0 + kk) * N + bn + n];
        }
        __syncthreads();
        #pragma unroll
        for (int kk = 0; kk < 16; ++kk) {
            float a[4], b[4];
            #pragma unroll
            for (int i = 0; i < 4; ++i) a[i] = As[kk][ty * 4 + i];
            #pragma unroll
            for (int j = 0; j < 4; ++j) b[j] = Bs[kk][tx * 4 + j];
            #pragma unroll
            for (int i = 0; i < 4; ++i)
                #pragma unroll
                for (int j = 0; j < 4; ++j)
                    acc[i][j] += a[i] * b[j];
        }
        __syncthreads();
    }

    float alpha = 1.0f, beta = 0.0f;
    if (blend) {
        float sv = *skipv;
        alpha = 1.0f / (1.0f + expf(-sv));
        beta = 1.0f - alpha;
    }
    #pragma unroll
    for (int i = 0; i < 4; ++i) {
        int gm = bm + ty * 4 + i;
        if (gm >= M) continue;
        #pragma unroll
        for (int j = 0; j < 4; ++j) {
            int gn = bn + tx * 4 + j;
            float val = acc[i][j] * a_scale + bias[gn];
            if (blend) val = alpha * val + beta * Hprev[(size_t)gm * N + gn];
            C[(size_t)gm * N + gn] = val;
        }
    }
}

// per (edge, head): score = (q[dst]·k[src]) * ea / sqrt(DK); atomic segment-max
__global__ void edge_score_kernel(const float* __restrict__ q, const float* __restrict__ k,
                                  const int* __restrict__ src, const int* __restrict__ dst,
                                  const float* __restrict__ sim,
                                  const float* __restrict__ ew, const float* __restrict__ eb,
                                  float* __restrict__ score, float* __restrict__ m, int E)
{
    int gid = blockIdx.x * blockDim.x + threadIdx.x;
    if (gid >= E * NHEAD) return;
    int e = gid >> 3, hh = gid & 7;
    int s_ = src[e], d_ = dst[e];
    const float4* qp = (const float4*)(q + (size_t)d_ * 256 + hh * DKDIM);
    const float4* kp = (const float4*)(k + (size_t)s_ * 256 + hh * DKDIM);
    float acc = 0.0f;
    #pragma unroll
    for (int i = 0; i < 8; ++i) {
        float4 a = qp[i], b = kp[i];
        acc += a.x * b.x + a.y * b.y + a.z * b.z + a.w * b.w;
    }
    float ea = sim[e] * ew[0] + eb[0];
    float sc = acc * ea * 0.17677669529663687f;  // 1/sqrt(32)
    score[gid] = sc;
    atomicMaxFloat(&m[d_ * NHEAD + hh], sc);
}

// per (edge, head): ex = exp(score - m[dst]); atomic segment-sum (in-place on score)
__global__ void edge_exp_kernel(const int* __restrict__ dst, const float* __restrict__ m,
                                float* __restrict__ score_ex, float* __restrict__ ssum, int E)
{
    int gid = blockIdx.x * blockDim.x + threadIdx.x;
    if (gid >= E * NHEAD) return;
    int e = gid >> 3, hh = gid & 7;
    int d_ = dst[e];
    float ex = expf(score_ex[gid] - m[d_ * NHEAD + hh]);
    score_ex[gid] = ex;
    atomicAdd(&ssum[d_ * NHEAD + hh], ex);
}

// per (edge, channel d in 0..255): agg[dst,d] += v[src,d] * (ex/s)
__global__ void edge_agg_kernel(const int* __restrict__ src, const int* __restrict__ dst,
                                const float* __restrict__ v, const float* __restrict__ ex,
                                const float* __restrict__ ssum, float* __restrict__ agg, int E)
{
    int gid = blockIdx.x * blockDim.x + threadIdx.x;
    int e = gid >> 8, d = gid & 255;
    if (e >= E) return;
    int hh = d >> 5;
    int s_ = src[e], dd = dst[e];
    float attn = ex[e * NHEAD + hh] / ssum[dd * NHEAD + hh];
    atomicAdd(&agg[(size_t)dd * 256 + d], v[(size_t)s_ * 256 + d] * attn);
}

__global__ void colsum_kernel(const float* __restrict__ h, float* __restrict__ out, int N)
{
    int c = threadIdx.x;  // 256 threads
    float acc = 0.0f;
    for (int r = blockIdx.x; r < N; r += gridDim.x)
        acc += h[(size_t)r * 256 + c];
    atomicAdd(&out[c], acc);
}

// mean -> pred(t=0) -> head1 -> head ; writes c[512] = g@head_w + head_b
__global__ __launch_bounds__(512)
void head_kernel(const float* __restrict__ colsum, float n_img,
                 const float* __restrict__ pred_w, const float* __restrict__ pred_b,
                 const float* __restrict__ head1_w, const float* __restrict__ head1_b,
                 const float* __restrict__ head_w, const float* __restrict__ head_b,
                 float* __restrict__ cvec)
{
    __shared__ float mean[256], o0[256], g[512];
    int t = threadIdx.x;
    if (t < 256) mean[t] = colsum[t] / n_img;
    __syncthreads();
    if (t < 256) {
        float acc = pred_b[t];
        for (int k = 0; k < 256; ++k) acc += mean[k] * pred_w[k * 256 + t];
        o0[t] = acc;
    }
    __syncthreads();
    {
        float acc = head1_b[t];
        for (int k = 0; k < 256; ++k) acc += o0[k] * head1_w[k * 512 + t];
        g[t] = acc;
    }
    __syncthreads();
    {
        float acc = head_b[t];
        for (int k = 0; k < 512; ++k) acc += g[k] * head_w[k * 512 + t];
        cvec[t] = acc;
    }
}

extern "C" void kernel_launch(void* const* d_in, const int* in_sizes, int n_in,
                              void* d_out, int out_size, void* d_ws, size_t ws_size,
                              hipStream_t stream)
{
    const int NI = 20000, NG = 10000, NT = 5000, E = 100000;
    const int ns[3] = {NI, NG, NT};
    const size_t offn[3] = {0, (size_t)NI * 256, (size_t)(NI + NG) * 256};

    const float* feat[3] = {(const float*)d_in[0], (const float*)d_in[1], (const float*)d_in[2]};
    const float* adapt_w = (const float*)d_in[3];
    const float* adapt_b = (const float*)d_in[4];
    const float* k_w = (const float*)d_in[5];
    const float* k_b = (const float*)d_in[6];
    const float* q_w = (const float*)d_in[7];
    const float* q_b = (const float*)d_in[8];
    const float* v_w = (const float*)d_in[9];
    const float* v_b = (const float*)d_in[10];
    const float* a_w = (const float*)d_in[11];
    const float* a_b = (const float*)d_in[12];
    const float* e_w = (const float*)d_in[13];
    const float* e_b = (const float*)d_in[14];
    const float* skip = (const float*)d_in[15];
    const float* pred_w = (const float*)d_in[16];
    const float* pred_b = (const float*)d_in[17];
    // d_in[18] attn_w: dead (softmax over singleton axis == 1)
    const float* head1_w = (const float*)d_in[19];
    const float* head1_b = (const float*)d_in[20];
    const float* head_w = (const float*)d_in[21];
    const float* head_b = (const float*)d_in[22];
    const float* sim[6];
    for (int i = 0; i < 6; ++i) sim[i] = (const float*)d_in[23 + i];
    const int* srcp[6];
    const int* dstp[6];
    for (int i = 0; i < 6; ++i) {
        srcp[i] = (const int*)d_in[29 + 2 * i];
        dstp[i] = (const int*)d_in[30 + 2 * i];
    }
    const int est[6] = {0, 1, 0, 2, 1, 2};
    const int edt[6] = {1, 0, 2, 0, 2, 1};

    float* ws = (float*)d_ws;
    size_t off = 0;
    auto alloc = [&](size_t n) { float* p = ws + off; off += n; return p; };
    const size_t NTOT = (size_t)(NI + NG + NT) * 256;
    float* hb   = alloc(NTOT);
    float* qb   = alloc(NTOT);
    float* kb   = alloc(NTOT);
    float* vb   = alloc(NTOT);
    float* aggb = alloc(NTOT);
    float* exb  = alloc((size_t)E * NHEAD);
    float* mb   = alloc((size_t)NI * NHEAD);
    float* sb   = alloc((size_t)NI * NHEAD);
    float* csum = alloc(256);
    float* cvec = alloc(512);

    auto gemm = [&](const float* A, const float* W, const float* b, float* C,
                    const float* Hp, const float* sk, int M, int N, int K,
                    float asc, int blend) {
        dim3 g((M + 63) / 64, N / 64);
        hipLaunchKernelGGL(gemm_kernel, g, dim3(256), 0, stream,
                           A, W, b, C, Hp, sk, M, N, K, asc, blend);
    };

    // adapt: h[t] = feats[t] @ adapt_w[t] + adapt_b[t]
    for (int t = 0; t < 3; ++t)
        gemm(feat[t], adapt_w + (size_t)t * 512 * 256, adapt_b + t * 256,
             hb + offn[t], nullptr, nullptr, ns[t], 256, 512, 1.0f, 0);

    for (int l = 0; l < 2; ++l) {
        for (int t = 0; t < 3; ++t) {
            size_t wo = ((size_t)l * 3 + t) * 256 * 256, bo = ((size_t)l * 3 + t) * 256;
            gemm(hb + offn[t], q_w + wo, q_b + bo, qb + offn[t], nullptr, nullptr, ns[t], 256, 256, 1.0f, 0);
            gemm(hb + offn[t], k_w + wo, k_b + bo, kb + offn[t], nullptr, nullptr, ns[t], 256, 256, 1.0f, 0);
            gemm(hb + offn[t], v_w + wo, v_b + bo, vb + offn[t], nullptr, nullptr, ns[t], 256, 256, 1.0f, 0);
        }
        hipMemsetAsync(aggb, 0, NTOT * sizeof(float), stream);
        for (int i = 0; i < 6; ++i) {
            int st = est[i], dt = edt[i];
            int nd = ns[dt];
            hipLaunchKernelGGL(fill_kernel, dim3((nd * NHEAD + 255) / 256), dim3(256), 0, stream,
                               mb, -INFINITY, nd * NHEAD);
            hipMemsetAsync(sb, 0, (size_t)nd * NHEAD * sizeof(float), stream);
            int nEH = E * NHEAD;
            hipLaunchKernelGGL(edge_score_kernel, dim3((nEH + 255) / 256), dim3(256), 0, stream,
                               qb + offn[dt], kb + offn[st], srcp[i], dstp[i], sim[i],
                               e_w + l, e_b + l, exb, mb, E);
            hipLaunchKernelGGL(edge_exp_kernel, dim3((nEH + 255) / 256), dim3(256), 0, stream,
                               dstp[i], mb, exb, sb, E);
            hipLaunchKernelGGL(edge_agg_kernel, dim3(E), dim3(256), 0, stream,
                               srcp[i], dstp[i], vb + offn[st], exb, sb, aggb + offn[dt], E);
        }
        for (int t = 0; t < 3; ++t) {
            size_t wo = ((size_t)l * 3 + t) * 256 * 256, bo = ((size_t)l * 3 + t) * 256;
            gemm(aggb + offn[t], a_w + wo, a_b + bo, hb + offn[t],
                 hb + offn[t], skip + l * 3 + t, ns[t], 256, 256, 0.5f, 1);
        }
    }

    hipMemsetAsync(csum, 0, 256 * sizeof(float), stream);
    hipLaunchKernelGGL(colsum_kernel, dim3(128), dim3(256), 0, stream, hb, csum, NI);
    hipLaunchKernelGGL(head_kernel, dim3(1), dim3(512), 0, stream,
                       csum, (float)NI, pred_w, pred_b, head1_w, head1_b, head_w, head_b, cvec);

    // out = feats[0] @ head_w + cvec
    gemm(feat[0], head_w, cvec, (float*)d_out, nullptr, nullptr, NI, 512, 512, 1.0f, 0);
}

// Round 2
// 2285.066 us; speedup vs baseline: 1.3819x; 1.3819x over previous
//
#include <hip/hip_runtime.h>
#include <hip/hip_bf16.h>
#include <math.h>

#define NHEAD 8
#define DKDIM 32

// C[M,N] = a_scale*(A[M,K] @ W[K,N]) + bias[N]
// blend: C = alpha*that + (1-alpha)*Hprev, alpha = sigmoid(*skipv). In-place safe (C==Hprev).
__global__ __launch_bounds__(256)
void gemm_kernel(const float* __restrict__ A, const float* __restrict__ W,
                 const float* __restrict__ bias, float* __restrict__ C,
                 const float* __restrict__ Hprev, const float* __restrict__ skipv,
                 int M, int N, int K, float a_scale, int blend)
{
    __shared__ float As[16][65];   // [k][m], padded: conflict-free transpose write
    __shared__ float Bs[16][64];   // [k][n]
    const int bm = blockIdx.x * 64;
    const int bn = blockIdx.y * 64;
    const int tid = threadIdx.x;
    const int tx = tid & 15;       // n direction
    const int ty = tid >> 4;       // m direction
    float acc[4][4] = {};

    for (int k0 = 0; k0 < K; k0 += 16) {
        #pragma unroll
        for (int it = 0; it < 4; ++it) {
            int i = tid + it * 256;
            int m = i >> 4, kk = i & 15;
            int gm = bm + m;
            As[kk][m] = (gm < M) ? A[(size_t)gm * K + k0 + kk] : 0.0f;
        }
        #pragma unroll
        for (int it = 0; it < 4; ++it) {
            int i = tid + it * 256;
            int kk = i >> 6, n = i & 63;
            Bs[kk][n] = W[(size_t)(k0 + kk) * N + bn + n];
        }
        __syncthreads();
        #pragma unroll
        for (int kk = 0; kk < 16; ++kk) {
            float a[4], b[4];
            #pragma unroll
            for (int i = 0; i < 4; ++i) a[i] = As[kk][ty * 4 + i];
            #pragma unroll
            for (int j = 0; j < 4; ++j) b[j] = Bs[kk][tx * 4 + j];
            #pragma unroll
            for (int i = 0; i < 4; ++i)
                #pragma unroll
                for (int j = 0; j < 4; ++j)
                    acc[i][j] += a[i] * b[j];
        }
        __syncthreads();
    }

    float alpha = 1.0f, beta = 0.0f;
    if (blend) {
        float sv = *skipv;
        alpha = 1.0f / (1.0f + expf(-sv));
        beta = 1.0f - alpha;
    }
    #pragma unroll
    for (int i = 0; i < 4; ++i) {
        int gm = bm + ty * 4 + i;
        if (gm >= M) continue;
        #pragma unroll
        for (int j = 0; j < 4; ++j) {
            int gn = bn + tx * 4 + j;
            float val = acc[i][j] * a_scale + bias[gn];
            if (blend) val = alpha * val + beta * Hprev[(size_t)gm * N + gn];
            C[(size_t)gm * N + gn] = val;
        }
    }
}

// ---------------- CSR build ----------------
__global__ void hist_kernel(const int* __restrict__ dst, int* __restrict__ deg, int E) {
    int e = blockIdx.x * blockDim.x + threadIdx.x;
    if (e < E) atomicAdd(&deg[dst[e]], 1);
}

__global__ __launch_bounds__(256)
void scan_kernel(const int* __restrict__ deg, int* __restrict__ rowptr,
                 int* __restrict__ cursor, int nd)
{
    __shared__ int buf[256];
    __shared__ int carry_s;
    int t = threadIdx.x;
    if (t == 0) carry_s = 0;
    __syncthreads();
    for (int base = 0; base < nd; base += 256) {
        int x = (base + t < nd) ? deg[base + t] : 0;
        buf[t] = x;
        __syncthreads();
        #pragma unroll
        for (int off = 1; off < 256; off <<= 1) {
            int y = (t >= off) ? buf[t - off] : 0;
            __syncthreads();
            buf[t] += y;
            __syncthreads();
        }
        int excl = buf[t] - x + carry_s;
        if (base + t < nd) { rowptr[base + t] = excl; cursor[base + t] = excl; }
        __syncthreads();
        if (t == 255) carry_s += buf[255];
        __syncthreads();
    }
    if (t == 0) rowptr[nd] = carry_s;
}

__global__ void scatter_kernel(const int* __restrict__ dst, int* __restrict__ cursor,
                               int* __restrict__ eidx, int E) {
    int e = blockIdx.x * blockDim.x + threadIdx.x;
    if (e < E) {
        int j = atomicAdd(&cursor[dst[e]], 1);
        eidx[j] = e;
    }
}

// ---------------- fused per-dst-node edge softmax + aggregation ----------------
// one 64-thread wave per dst node; thread t owns channels 4t..4t+3 (head = t>>3).
// online softmax over in-edges; writes (or accumulates) agg[d, :].
__global__ __launch_bounds__(64)
void node_attn_kernel(const float* __restrict__ q, const float* __restrict__ k,
                      const float* __restrict__ v, const int* __restrict__ rowptr,
                      const int* __restrict__ eidx, const int* __restrict__ srcarr,
                      const float* __restrict__ sim, const float* __restrict__ ewp,
                      const float* __restrict__ ebp, float* __restrict__ agg,
                      int accumulate)
{
    const int d = blockIdx.x;
    const int t = threadIdx.x;
    const float ewv = ewp[0], ebv = ebp[0];
    const float4 qv = ((const float4*)q)[(size_t)d * 64 + t];
    const int beg = rowptr[d], end = rowptr[d + 1];

    float m = -INFINITY, s = 0.0f;
    float4 acc = {0.f, 0.f, 0.f, 0.f};

    for (int j = beg; j < end; ++j) {
        int e = eidx[j];
        int sN = srcarr[e];
        float4 kv = ((const float4*)k)[(size_t)sN * 64 + t];
        float4 vv = ((const float4*)v)[(size_t)sN * 64 + t];
        float dot = qv.x * kv.x + qv.y * kv.y + qv.z * kv.z + qv.w * kv.w;
        // reduce over the 8 lanes of this head (channels 32*h .. 32*h+31)
        dot += __shfl_xor(dot, 1);
        dot += __shfl_xor(dot, 2);
        dot += __shfl_xor(dot, 4);
        float sc = dot * (sim[e] * ewv + ebv) * 0.17677669529663687f; // 1/sqrt(32)
        if (sc > m) {                 // rescale old state (first iter: exp(-inf)=0)
            float r = __expf(m - sc);
            s *= r;
            acc.x *= r; acc.y *= r; acc.z *= r; acc.w *= r;
            m = sc;
        }
        float ex = __expf(sc - m);
        s += ex;
        acc.x += ex * vv.x; acc.y += ex * vv.y; acc.z += ex * vv.z; acc.w += ex * vv.w;
    }

    float inv = (end > beg) ? 1.0f / s : 0.0f;
    float4 res = {acc.x * inv, acc.y * inv, acc.z * inv, acc.w * inv};
    float4* outp = (float4*)agg + (size_t)d * 64 + t;
    if (accumulate) {
        float4 old = *outp;
        res.x += old.x; res.y += old.y; res.z += old.z; res.w += old.w;
    }
    *outp = res;
}

__global__ void colsum_kernel(const float* __restrict__ h, float* __restrict__ out, int N)
{
    int c = threadIdx.x;  // 256 threads
    float acc = 0.0f;
    for (int r = blockIdx.x; r < N; r += gridDim.x)
        acc += h[(size_t)r * 256 + c];
    atomicAdd(&out[c], acc);
}

// mean -> pred(t=0) -> head1 -> head ; writes c[512] = g@head_w + head_b
__global__ __launch_bounds__(512)
void head_kernel(const float* __restrict__ colsum, float n_img,
                 const float* __restrict__ pred_w, const float* __restrict__ pred_b,
                 const float* __restrict__ head1_w, const float* __restrict__ head1_b,
                 const float* __restrict__ head_w, const float* __restrict__ head_b,
                 float* __restrict__ cvec)
{
    __shared__ float mean[256], o0[256], g[512];
    int t = threadIdx.x;
    if (t < 256) mean[t] = colsum[t] / n_img;
    __syncthreads();
    if (t < 256) {
        float acc = pred_b[t];
        for (int k = 0; k < 256; ++k) acc += mean[k] * pred_w[k * 256 + t];
        o0[t] = acc;
    }
    __syncthreads();
    {
        float acc = head1_b[t];
        for (int k = 0; k < 256; ++k) acc += o0[k] * head1_w[k * 512 + t];
        g[t] = acc;
    }
    __syncthreads();
    {
        float acc = head_b[t];
        for (int k = 0; k < 512; ++k) acc += g[k] * head_w[k * 512 + t];
        cvec[t] = acc;
    }
}

extern "C" void kernel_launch(void* const* d_in, const int* in_sizes, int n_in,
                              void* d_out, int out_size, void* d_ws, size_t ws_size,
                              hipStream_t stream)
{
    const int NI = 20000, NG = 10000, NT = 5000, E = 100000;
    const int ns[3] = {NI, NG, NT};
    const size_t offn[3] = {0, (size_t)NI * 256, (size_t)(NI + NG) * 256};

    const float* feat[3] = {(const float*)d_in[0], (const float*)d_in[1], (const float*)d_in[2]};
    const float* adapt_w = (const float*)d_in[3];
    const float* adapt_b = (const float*)d_in[4];
    const float* k_w = (const float*)d_in[5];
    const float* k_b = (const float*)d_in[6];
    const float* q_w = (const float*)d_in[7];
    const float* q_b = (const float*)d_in[8];
    const float* v_w = (const float*)d_in[9];
    const float* v_b = (const float*)d_in[10];
    const float* a_w = (const float*)d_in[11];
    const float* a_b = (const float*)d_in[12];
    const float* e_w = (const float*)d_in[13];
    const float* e_b = (const float*)d_in[14];
    const float* skip = (const float*)d_in[15];
    const float* pred_w = (const float*)d_in[16];
    const float* pred_b = (const float*)d_in[17];
    // d_in[18] attn_w: dead (softmax over singleton axis == 1)
    const float* head1_w = (const float*)d_in[19];
    const float* head1_b = (const float*)d_in[20];
    const float* head_w = (const float*)d_in[21];
    const float* head_b = (const float*)d_in[22];
    const float* sim[6];
    for (int i = 0; i < 6; ++i) sim[i] = (const float*)d_in[23 + i];
    const int* srcp[6];
    const int* dstp[6];
    for (int i = 0; i < 6; ++i) {
        srcp[i] = (const int*)d_in[29 + 2 * i];
        dstp[i] = (const int*)d_in[30 + 2 * i];
    }
    const int est[6] = {0, 1, 0, 2, 1, 2};
    const int edt[6] = {1, 0, 2, 0, 2, 1};

    float* ws = (float*)d_ws;
    size_t off = 0;
    auto alloc = [&](size_t n) { float* p = ws + off; off += n; return p; };
    const size_t NTOT = (size_t)(NI + NG + NT) * 256;
    float* hb   = alloc(NTOT);
    float* qb   = alloc(NTOT);
    float* kb   = alloc(NTOT);
    float* vb   = alloc(NTOT);
    float* aggb = alloc(NTOT);
    float* csum = alloc(256);
    float* cvec = alloc(512);
    // int pool for CSR
    int* ipool = (int*)(ws + off);
    int* deg    = ipool;
    int* cursor = ipool + 20001;
    int* p      = ipool + 2 * 20001;
    int* rowptr_[6];
    int* eidx_[6];
    for (int i = 0; i < 6; ++i) {
        rowptr_[i] = p; p += ns[edt[i]] + 1;
        eidx_[i]   = p; p += E;
    }

    auto gemm = [&](const float* A, const float* W, const float* b, float* C,
                    const float* Hp, const float* sk, int M, int N, int K,
                    float asc, int blend) {
        dim3 g((M + 63) / 64, N / 64);
        hipLaunchKernelGGL(gemm_kernel, g, dim3(256), 0, stream,
                           A, W, b, C, Hp, sk, M, N, K, asc, blend);
    };

    // ---- build CSR per etype (reused by both layers) ----
    for (int i = 0; i < 6; ++i) {
        int nd = ns[edt[i]];
        hipMemsetAsync(deg, 0, (size_t)nd * sizeof(int), stream);
        hipLaunchKernelGGL(hist_kernel, dim3((E + 255) / 256), dim3(256), 0, stream,
                           dstp[i], deg, E);
        hipLaunchKernelGGL(scan_kernel, dim3(1), dim3(256), 0, stream,
                           deg, rowptr_[i], cursor, nd);
        hipLaunchKernelGGL(scatter_kernel, dim3((E + 255) / 256), dim3(256), 0, stream,
                           dstp[i], cursor, eidx_[i], E);
    }

    // adapt: h[t] = feats[t] @ adapt_w[t] + adapt_b[t]
    for (int t = 0; t < 3; ++t)
        gemm(feat[t], adapt_w + (size_t)t * 512 * 256, adapt_b + t * 256,
             hb + offn[t], nullptr, nullptr, ns[t], 256, 512, 1.0f, 0);

    for (int l = 0; l < 2; ++l) {
        for (int t = 0; t < 3; ++t) {
            size_t wo = ((size_t)l * 3 + t) * 256 * 256, bo = ((size_t)l * 3 + t) * 256;
            gemm(hb + offn[t], q_w + wo, q_b + bo, qb + offn[t], nullptr, nullptr, ns[t], 256, 256, 1.0f, 0);
            gemm(hb + offn[t], k_w + wo, k_b + bo, kb + offn[t], nullptr, nullptr, ns[t], 256, 256, 1.0f, 0);
            gemm(hb + offn[t], v_w + wo, v_b + bo, vb + offn[t], nullptr, nullptr, ns[t], 256, 256, 1.0f, 0);
        }
        // fused edge softmax + aggregation (gather, no atomics)
        for (int i = 0; i < 6; ++i) {
            int st = est[i], dt = edt[i];
            hipLaunchKernelGGL(node_attn_kernel, dim3(ns[dt]), dim3(64), 0, stream,
                               qb + offn[dt], kb + offn[st], vb + offn[st],
                               rowptr_[i], eidx_[i], srcp[i], sim[i],
                               e_w + l, e_b + l, aggb + offn[dt], (i >= 3) ? 1 : 0);
        }
        for (int t = 0; t < 3; ++t) {
            size_t wo = ((size_t)l * 3 + t) * 256 * 256, bo = ((size_t)l * 3 + t) * 256;
            gemm(aggb + offn[t], a_w + wo, a_b + bo, hb + offn[t],
                 hb + offn[t], skip + l * 3 + t, ns[t], 256, 256, 0.5f, 1);
        }
    }

    hipMemsetAsync(csum, 0, 256 * sizeof(float), stream);
    hipLaunchKernelGGL(colsum_kernel, dim3(128), dim3(256), 0, stream, hb, csum, NI);
    hipLaunchKernelGGL(head_kernel, dim3(1), dim3(512), 0, stream,
                       csum, (float)NI, pred_w, pred_b, head1_w, head1_b, head_w, head_b, cvec);

    // out = feats[0] @ head_w + cvec
    gemm(feat[0], head_w, cvec, (float*)d_out, nullptr, nullptr, NI, 512, 512, 1.0f, 0);
}

// Round 3
// 1591.205 us; speedup vs baseline: 1.9845x; 1.4361x over previous
//
#include <hip/hip_runtime.h>
#include <hip/hip_bf16.h>
#include <math.h>

#define NHEAD 8
#define DKDIM 32

typedef short v8s __attribute__((ext_vector_type(8)));
typedef float v4f __attribute__((ext_vector_type(4)));

__device__ __forceinline__ unsigned short f2bf(float f) {
    unsigned int u = __float_as_uint(f);
    u += 0x7fff + ((u >> 16) & 1);   // round-to-nearest-even
    return (unsigned short)(u >> 16);
}

// ---------------- weight transpose + convert: W[K][N] fp32 -> Wt[N][K] bf16 ----------------
__global__ __launch_bounds__(256)
void wcvt_kernel(const float* __restrict__ W, unsigned short* __restrict__ Wt, int K, int N)
{
    __shared__ float tile[32][33];
    const int b = blockIdx.z;
    const float* Wb = W + (size_t)b * K * N;
    unsigned short* Wtb = Wt + (size_t)b * K * N;
    const int k0 = blockIdx.x * 32, n0 = blockIdx.y * 32;
    const int x = threadIdx.x & 31, y = threadIdx.x >> 5;   // y: 0..7
    #pragma unroll
    for (int j = 0; j < 4; ++j)
        tile[y + 8 * j][x] = Wb[(size_t)(k0 + y + 8 * j) * N + n0 + x];
    __syncthreads();
    #pragma unroll
    for (int j = 0; j < 4; ++j)
        Wtb[(size_t)(n0 + y + 8 * j) * K + k0 + x] = f2bf(tile[x][y + 8 * j]);
}

// ---------------- bf16 MFMA GEMM ----------------
// C[M,N] = a_scale*(A[M,K]@W[K,N]) + bias[N]; A fp32 (converted on the fly), Wt = bf16 W^T [N][K].
// blend: C = alpha*that + (1-alpha)*Hprev, alpha = sigmoid(*skipv). In-place safe (C==Hprev).
// Tile 128x128, BK=32, 256 threads = 4 waves (2x2), each wave 4x4 frags of 16x16x32.
__global__ __launch_bounds__(256)
void mfma_gemm(const float* __restrict__ A, const unsigned short* __restrict__ Wt,
               const float* __restrict__ bias, float* __restrict__ C,
               const float* __restrict__ Hprev, const float* __restrict__ skipv,
               int M, int N, int K, float a_scale, int blend)
{
    __shared__ unsigned short As[128 * 32];  // [row][k] bf16, 8 KB
    __shared__ unsigned short Bs[128 * 32];  // [col][k] bf16, 8 KB
    const int bm = blockIdx.x * 128, bn = blockIdx.y * 128;
    const int tid = threadIdx.x;
    const int lane = tid & 63, w = tid >> 6, wr = w >> 1, wc = w & 1;
    const int l16 = lane & 15, lg = lane >> 4;

    v4f acc[4][4] = {};

    // staging: thread covers row sr, 16 k-elements at sc
    const int sr = tid >> 1, sc = (tid & 1) * 16;
    const int arow = bm + sr;
    const bool aok = arow < M;
    const float* ap = A + (size_t)arow * K + sc;
    const unsigned short* bp = Wt + (size_t)(bn + sr) * K + sc;

    const int abase = (wr * 64 + l16) * 32 + lg * 8;
    const int bbase = (wc * 64 + l16) * 32 + lg * 8;

    for (int k0 = 0; k0 < K; k0 += 32) {
        float4 a0 = {0,0,0,0}, a1 = a0, a2 = a0, a3 = a0;
        if (aok) {
            a0 = *(const float4*)(ap + k0);
            a1 = *(const float4*)(ap + k0 + 4);
            a2 = *(const float4*)(ap + k0 + 8);
            a3 = *(const float4*)(ap + k0 + 12);
        }
        uint4 b0 = *(const uint4*)(bp + k0);
        uint4 b1 = *(const uint4*)(bp + k0 + 8);

        if (k0) __syncthreads();   // previous tile fully consumed

        uint4 w0, w1;
        w0.x = (unsigned int)f2bf(a0.x) | ((unsigned int)f2bf(a0.y) << 16);
        w0.y = (unsigned int)f2bf(a0.z) | ((unsigned int)f2bf(a0.w) << 16);
        w0.z = (unsigned int)f2bf(a1.x) | ((unsigned int)f2bf(a1.y) << 16);
        w0.w = (unsigned int)f2bf(a1.z) | ((unsigned int)f2bf(a1.w) << 16);
        w1.x = (unsigned int)f2bf(a2.x) | ((unsigned int)f2bf(a2.y) << 16);
        w1.y = (unsigned int)f2bf(a2.z) | ((unsigned int)f2bf(a2.w) << 16);
        w1.z = (unsigned int)f2bf(a3.x) | ((unsigned int)f2bf(a3.y) << 16);
        w1.w = (unsigned int)f2bf(a3.z) | ((unsigned int)f2bf(a3.w) << 16);
        *(uint4*)&As[sr * 32 + sc]     = w0;
        *(uint4*)&As[sr * 32 + sc + 8] = w1;
        *(uint4*)&Bs[sr * 32 + sc]     = b0;
        *(uint4*)&Bs[sr * 32 + sc + 8] = b1;
        __syncthreads();

        v8s af[4], bf[4];
        #pragma unroll
        for (int f = 0; f < 4; ++f) af[f] = *(const v8s*)&As[abase + f * 512];
        #pragma unroll
        for (int f = 0; f < 4; ++f) bf[f] = *(const v8s*)&Bs[bbase + f * 512];
        #pragma unroll
        for (int i = 0; i < 4; ++i)
            #pragma unroll
            for (int j = 0; j < 4; ++j)
                acc[i][j] = __builtin_amdgcn_mfma_f32_16x16x32_bf16(af[i], bf[j], acc[i][j], 0, 0, 0);
    }

    float alpha = 1.0f, beta = 0.0f;
    if (blend) {
        float sv = *skipv;
        alpha = 1.0f / (1.0f + expf(-sv));
        beta = 1.0f - alpha;
    }
    const int row0 = bm + wr * 64, col0 = bn + wc * 64;
    float bv[4];
    #pragma unroll
    for (int fn = 0; fn < 4; ++fn) bv[fn] = bias[col0 + fn * 16 + l16];
    #pragma unroll
    for (int fm = 0; fm < 4; ++fm) {
        #pragma unroll
        for (int i = 0; i < 4; ++i) {
            int gm = row0 + fm * 16 + lg * 4 + i;
            if (gm >= M) continue;
            #pragma unroll
            for (int fn = 0; fn < 4; ++fn) {
                int gn = col0 + fn * 16 + l16;
                float val = acc[fm][fn][i] * a_scale + bv[fn];
                if (blend) val = alpha * val + beta * Hprev[(size_t)gm * N + gn];
                C[(size_t)gm * N + gn] = val;
            }
        }
    }
}

// ---------------- fp32 GEMM (kept for the final head GEMM: full precision) ----------------
__global__ __launch_bounds__(256)
void gemm_kernel(const float* __restrict__ A, const float* __restrict__ W,
                 const float* __restrict__ bias, float* __restrict__ C,
                 int M, int N, int K)
{
    __shared__ float As[16][65];
    __shared__ float Bs[16][64];
    const int bm = blockIdx.x * 64;
    const int bn = blockIdx.y * 64;
    const int tid = threadIdx.x;
    const int tx = tid & 15;
    const int ty = tid >> 4;
    float acc[4][4] = {};

    for (int k0 = 0; k0 < K; k0 += 16) {
        #pragma unroll
        for (int it = 0; it < 4; ++it) {
            int i = tid + it * 256;
            int m = i >> 4, kk = i & 15;
            int gm = bm + m;
            As[kk][m] = (gm < M) ? A[(size_t)gm * K + k0 + kk] : 0.0f;
        }
        #pragma unroll
        for (int it = 0; it < 4; ++it) {
            int i = tid + it * 256;
            int kk = i >> 6, n = i & 63;
            Bs[kk][n] = W[(size_t)(k0 + kk) * N + bn + n];
        }
        __syncthreads();
        #pragma unroll
        for (int kk = 0; kk < 16; ++kk) {
            float a[4], b[4];
            #pragma unroll
            for (int i = 0; i < 4; ++i) a[i] = As[kk][ty * 4 + i];
            #pragma unroll
            for (int j = 0; j < 4; ++j) b[j] = Bs[kk][tx * 4 + j];
            #pragma unroll
            for (int i = 0; i < 4; ++i)
                #pragma unroll
                for (int j = 0; j < 4; ++j)
                    acc[i][j] += a[i] * b[j];
        }
        __syncthreads();
    }

    #pragma unroll
    for (int i = 0; i < 4; ++i) {
        int gm = bm + ty * 4 + i;
        if (gm >= M) continue;
        #pragma unroll
        for (int j = 0; j < 4; ++j) {
            int gn = bn + tx * 4 + j;
            C[(size_t)gm * N + gn] = acc[i][j] + bias[gn];
        }
    }
}

// ---------------- CSR build ----------------
__global__ void hist_kernel(const int* __restrict__ dst, int* __restrict__ deg, int E) {
    int e = blockIdx.x * blockDim.x + threadIdx.x;
    if (e < E) atomicAdd(&deg[dst[e]], 1);
}

__global__ __launch_bounds__(256)
void scan_kernel(const int* __restrict__ deg, int* __restrict__ rowptr,
                 int* __restrict__ cursor, int nd)
{
    __shared__ int buf[256];
    __shared__ int carry_s;
    int t = threadIdx.x;
    if (t == 0) carry_s = 0;
    __syncthreads();
    for (int base = 0; base < nd; base += 256) {
        int x = (base + t < nd) ? deg[base + t] : 0;
        buf[t] = x;
        __syncthreads();
        #pragma unroll
        for (int off = 1; off < 256; off <<= 1) {
            int y = (t >= off) ? buf[t - off] : 0;
            __syncthreads();
            buf[t] += y;
            __syncthreads();
        }
        int excl = buf[t] - x + carry_s;
        if (base + t < nd) { rowptr[base + t] = excl; cursor[base + t] = excl; }
        __syncthreads();
        if (t == 255) carry_s += buf[255];
        __syncthreads();
    }
    if (t == 0) rowptr[nd] = carry_s;
}

__global__ void scatter_kernel(const int* __restrict__ dst, int* __restrict__ cursor,
                               int* __restrict__ eidx, int E) {
    int e = blockIdx.x * blockDim.x + threadIdx.x;
    if (e < E) {
        int j = atomicAdd(&cursor[dst[e]], 1);
        eidx[j] = e;
    }
}

// ---------------- fused per-dst-node edge softmax + aggregation ----------------
__global__ __launch_bounds__(64)
void node_attn_kernel(const float* __restrict__ q, const float* __restrict__ k,
                      const float* __restrict__ v, const int* __restrict__ rowptr,
                      const int* __restrict__ eidx, const int* __restrict__ srcarr,
                      const float* __restrict__ sim, const float* __restrict__ ewp,
                      const float* __restrict__ ebp, float* __restrict__ agg,
                      int accumulate)
{
    const int d = blockIdx.x;
    const int t = threadIdx.x;
    const float ewv = ewp[0], ebv = ebp[0];
    const float4 qv = ((const float4*)q)[(size_t)d * 64 + t];
    const int beg = rowptr[d], end = rowptr[d + 1];

    float m = -INFINITY, s = 0.0f;
    float4 acc = {0.f, 0.f, 0.f, 0.f};

    for (int j = beg; j < end; ++j) {
        int e = eidx[j];
        int sN = srcarr[e];
        float4 kv = ((const float4*)k)[(size_t)sN * 64 + t];
        float4 vv = ((const float4*)v)[(size_t)sN * 64 + t];
        float dot = qv.x * kv.x + qv.y * kv.y + qv.z * kv.z + qv.w * kv.w;
        dot += __shfl_xor(dot, 1);
        dot += __shfl_xor(dot, 2);
        dot += __shfl_xor(dot, 4);
        float sc = dot * (sim[e] * ewv + ebv) * 0.17677669529663687f; // 1/sqrt(32)
        if (sc > m) {
            float r = __expf(m - sc);
            s *= r;
            acc.x *= r; acc.y *= r; acc.z *= r; acc.w *= r;
            m = sc;
        }
        float ex = __expf(sc - m);
        s += ex;
        acc.x += ex * vv.x; acc.y += ex * vv.y; acc.z += ex * vv.z; acc.w += ex * vv.w;
    }

    float inv = (end > beg) ? 1.0f / s : 0.0f;
    float4 res = {acc.x * inv, acc.y * inv, acc.z * inv, acc.w * inv};
    float4* outp = (float4*)agg + (size_t)d * 64 + t;
    if (accumulate) {
        float4 old = *outp;
        res.x += old.x; res.y += old.y; res.z += old.z; res.w += old.w;
    }
    *outp = res;
}

__global__ void colsum_kernel(const float* __restrict__ h, float* __restrict__ out, int N)
{
    int c = threadIdx.x;
    float acc = 0.0f;
    for (int r = blockIdx.x; r < N; r += gridDim.x)
        acc += h[(size_t)r * 256 + c];
    atomicAdd(&out[c], acc);
}

__global__ __launch_bounds__(512)
void head_kernel(const float* __restrict__ colsum, float n_img,
                 const float* __restrict__ pred_w, const float* __restrict__ pred_b,
                 const float* __restrict__ head1_w, const float* __restrict__ head1_b,
                 const float* __restrict__ head_w, const float* __restrict__ head_b,
                 float* __restrict__ cvec)
{
    __shared__ float mean[256], o0[256], g[512];
    int t = threadIdx.x;
    if (t < 256) mean[t] = colsum[t] / n_img;
    __syncthreads();
    if (t < 256) {
        float acc = pred_b[t];
        for (int k = 0; k < 256; ++k) acc += mean[k] * pred_w[k * 256 + t];
        o0[t] = acc;
    }
    __syncthreads();
    {
        float acc = head1_b[t];
        for (int k = 0; k < 256; ++k) acc += o0[k] * head1_w[k * 512 + t];
        g[t] = acc;
    }
    __syncthreads();
    {
        float acc = head_b[t];
        for (int k = 0; k < 512; ++k) acc += g[k] * head_w[k * 512 + t];
        cvec[t] = acc;
    }
}

extern "C" void kernel_launch(void* const* d_in, const int* in_sizes, int n_in,
                              void* d_out, int out_size, void* d_ws, size_t ws_size,
                              hipStream_t stream)
{
    const int NI = 20000, NG = 10000, NT = 5000, E = 100000;
    const int ns[3] = {NI, NG, NT};
    const size_t offn[3] = {0, (size_t)NI * 256, (size_t)(NI + NG) * 256};

    const float* feat[3] = {(const float*)d_in[0], (const float*)d_in[1], (const float*)d_in[2]};
    const float* adapt_w = (const float*)d_in[3];
    const float* adapt_b = (const float*)d_in[4];
    const float* k_w = (const float*)d_in[5];
    const float* k_b = (const float*)d_in[6];
    const float* q_w = (const float*)d_in[7];
    const float* q_b = (const float*)d_in[8];
    const float* v_w = (const float*)d_in[9];
    const float* v_b = (const float*)d_in[10];
    const float* a_w = (const float*)d_in[11];
    const float* a_b = (const float*)d_in[12];
    const float* e_w = (const float*)d_in[13];
    const float* e_b = (const float*)d_in[14];
    const float* skip = (const float*)d_in[15];
    const float* pred_w = (const float*)d_in[16];
    const float* pred_b = (const float*)d_in[17];
    const float* head1_w = (const float*)d_in[19];
    const float* head1_b = (const float*)d_in[20];
    const float* head_w = (const float*)d_in[21];
    const float* head_b = (const float*)d_in[22];
    const float* sim[6];
    for (int i = 0; i < 6; ++i) sim[i] = (const float*)d_in[23 + i];
    const int* srcp[6];
    const int* dstp[6];
    for (int i = 0; i < 6; ++i) {
        srcp[i] = (const int*)d_in[29 + 2 * i];
        dstp[i] = (const int*)d_in[30 + 2 * i];
    }
    const int est[6] = {0, 1, 0, 2, 1, 2};
    const int edt[6] = {1, 0, 2, 0, 2, 1};

    float* ws = (float*)d_ws;
    size_t off = 0;
    auto alloc = [&](size_t n) { float* p = ws + off; off += n; return p; };
    const size_t NTOT = (size_t)(NI + NG + NT) * 256;
    float* hb   = alloc(NTOT);
    float* qb   = alloc(NTOT);
    float* kb   = alloc(NTOT);
    float* vb   = alloc(NTOT);
    float* aggb = alloc(NTOT);
    float* csum = alloc(256);
    float* cvec = alloc(512);
    // int pool for CSR
    int* ipool = (int*)(ws + off);
    int* deg    = ipool;
    int* cursor = ipool + 20001;
    int* p      = ipool + 2 * 20001;
    int* rowptr_[6];
    int* eidx_[6];
    for (int i = 0; i < 6; ++i) {
        rowptr_[i] = p; p += ns[edt[i]] + 1;
        eidx_[i]   = p; p += E;
    }
    // bf16 transposed weight pool (after int pool)
    unsigned short* wpool = (unsigned short*)p;
    unsigned short* adapt_wt = wpool;                       // 3 x [256][512]
    unsigned short* q_wt = adapt_wt + 3 * 512 * 256;        // 6 x [256][256]
    unsigned short* k_wt = q_wt + 6 * 65536;
    unsigned short* v_wt = k_wt + 6 * 65536;
    unsigned short* a_wt = v_wt + 6 * 65536;

    auto gemm_bf = [&](const float* A, const unsigned short* Wt, const float* b, float* C,
                       const float* Hp, const float* sk, int M, int N, int K,
                       float asc, int blend) {
        dim3 g((M + 127) / 128, N / 128);
        hipLaunchKernelGGL(mfma_gemm, g, dim3(256), 0, stream,
                           A, Wt, b, C, Hp, sk, M, N, K, asc, blend);
    };

    // ---- build CSR per etype (reused by both layers) ----
    for (int i = 0; i < 6; ++i) {
        int nd = ns[edt[i]];
        hipMemsetAsync(deg, 0, (size_t)nd * sizeof(int), stream);
        hipLaunchKernelGGL(hist_kernel, dim3((E + 255) / 256), dim3(256), 0, stream,
                           dstp[i], deg, E);
        hipLaunchKernelGGL(scan_kernel, dim3(1), dim3(256), 0, stream,
                           deg, rowptr_[i], cursor, nd);
        hipLaunchKernelGGL(scatter_kernel, dim3((E + 255) / 256), dim3(256), 0, stream,
                           dstp[i], cursor, eidx_[i], E);
    }

    // ---- transpose+convert weights to bf16 W^T ----
    hipLaunchKernelGGL(wcvt_kernel, dim3(16, 8, 3), dim3(256), 0, stream, adapt_w, adapt_wt, 512, 256);
    hipLaunchKernelGGL(wcvt_kernel, dim3(8, 8, 6), dim3(256), 0, stream, q_w, q_wt, 256, 256);
    hipLaunchKernelGGL(wcvt_kernel, dim3(8, 8, 6), dim3(256), 0, stream, k_w, k_wt, 256, 256);
    hipLaunchKernelGGL(wcvt_kernel, dim3(8, 8, 6), dim3(256), 0, stream, v_w, v_wt, 256, 256);
    hipLaunchKernelGGL(wcvt_kernel, dim3(8, 8, 6), dim3(256), 0, stream, a_w, a_wt, 256, 256);

    // adapt: h[t] = feats[t] @ adapt_w[t] + adapt_b[t]
    for (int t = 0; t < 3; ++t)
        gemm_bf(feat[t], adapt_wt + (size_t)t * 512 * 256, adapt_b + t * 256,
                hb + offn[t], nullptr, nullptr, ns[t], 256, 512, 1.0f, 0);

    for (int l = 0; l < 2; ++l) {
        for (int t = 0; t < 3; ++t) {
            size_t wo = ((size_t)l * 3 + t) * 65536, bo = ((size_t)l * 3 + t) * 256;
            gemm_bf(hb + offn[t], q_wt + wo, q_b + bo, qb + offn[t], nullptr, nullptr, ns[t], 256, 256, 1.0f, 0);
            gemm_bf(hb + offn[t], k_wt + wo, k_b + bo, kb + offn[t], nullptr, nullptr, ns[t], 256, 256, 1.0f, 0);
            gemm_bf(hb + offn[t], v_wt + wo, v_b + bo, vb + offn[t], nullptr, nullptr, ns[t], 256, 256, 1.0f, 0);
        }
        for (int i = 0; i < 6; ++i) {
            int st = est[i], dt = edt[i];
            hipLaunchKernelGGL(node_attn_kernel, dim3(ns[dt]), dim3(64), 0, stream,
                               qb + offn[dt], kb + offn[st], vb + offn[st],
                               rowptr_[i], eidx_[i], srcp[i], sim[i],
                               e_w + l, e_b + l, aggb + offn[dt], (i >= 3) ? 1 : 0);
        }
        for (int t = 0; t < 3; ++t) {
            size_t wo = ((size_t)l * 3 + t) * 65536, bo = ((size_t)l * 3 + t) * 256;
            gemm_bf(aggb + offn[t], a_wt + wo, a_b + bo, hb + offn[t],
                    hb + offn[t], skip + l * 3 + t, ns[t], 256, 256, 0.5f, 1);
        }
    }

    hipMemsetAsync(csum, 0, 256 * sizeof(float), stream);
    hipLaunchKernelGGL(colsum_kernel, dim3(128), dim3(256), 0, stream, hb, csum, NI);
    hipLaunchKernelGGL(head_kernel, dim3(1), dim3(512), 0, stream,
                       csum, (float)NI, pred_w, pred_b, head1_w, head1_b, head_w, head_b, cvec);

    // out = feats[0] @ head_w + cvec  (full fp32 for accuracy of the dominant direct term)
    {
        dim3 g((NI + 63) / 64, 512 / 64);
        hipLaunchKernelGGL(gemm_kernel, g, dim3(256), 0, stream,
                           feat[0], head_w, cvec, (float*)d_out, NI, 512, 512);
    }
}

// Round 4
// 1183.644 us; speedup vs baseline: 2.6678x; 1.3443x over previous
//
#include <hip/hip_runtime.h>
#include <hip/hip_bf16.h>
#include <math.h>

#define NHEAD 8
#define DKDIM 32

typedef short v8s __attribute__((ext_vector_type(8)));
typedef float v4f __attribute__((ext_vector_type(4)));
typedef unsigned short u16x4 __attribute__((ext_vector_type(4)));

__device__ __forceinline__ unsigned short f2bf(float f) {
    unsigned int u = __float_as_uint(f);
    u += 0x7fff + ((u >> 16) & 1);   // round-to-nearest-even
    return (unsigned short)(u >> 16);
}
__device__ __forceinline__ float bf2f(unsigned short h) {
    return __uint_as_float(((unsigned int)h) << 16);
}
__device__ __forceinline__ void split2(float f, unsigned short& h, unsigned short& l) {
    h = f2bf(f);
    float r = f - bf2f(h);      // exact
    l = f2bf(r);
}

// ---------------- weight transpose + convert: W[K][N] fp32 -> Wt[N][K] bf16 ----------------
__global__ __launch_bounds__(256)
void wcvt_kernel(const float* __restrict__ W, unsigned short* __restrict__ Wt, int K, int N)
{
    __shared__ float tile[32][33];
    const int b = blockIdx.z;
    const float* Wb = W + (size_t)b * K * N;
    unsigned short* Wtb = Wt + (size_t)b * K * N;
    const int k0 = blockIdx.x * 32, n0 = blockIdx.y * 32;
    const int x = threadIdx.x & 31, y = threadIdx.x >> 5;
    #pragma unroll
    for (int j = 0; j < 4; ++j)
        tile[y + 8 * j][x] = Wb[(size_t)(k0 + y + 8 * j) * N + n0 + x];
    __syncthreads();
    #pragma unroll
    for (int j = 0; j < 4; ++j)
        Wtb[(size_t)(n0 + y + 8 * j) * K + k0 + x] = f2bf(tile[x][y + 8 * j]);
}

// hi/lo split transpose for the final head GEMM
__global__ __launch_bounds__(256)
void wcvt_split_kernel(const float* __restrict__ W, unsigned short* __restrict__ Whi,
                       unsigned short* __restrict__ Wlo, int K, int N)
{
    __shared__ float tile[32][33];
    const int k0 = blockIdx.x * 32, n0 = blockIdx.y * 32;
    const int x = threadIdx.x & 31, y = threadIdx.x >> 5;
    #pragma unroll
    for (int j = 0; j < 4; ++j)
        tile[y + 8 * j][x] = W[(size_t)(k0 + y + 8 * j) * N + n0 + x];
    __syncthreads();
    #pragma unroll
    for (int j = 0; j < 4; ++j) {
        unsigned short h, l;
        split2(tile[x][y + 8 * j], h, l);
        size_t idx = (size_t)(n0 + y + 8 * j) * K + k0 + x;
        Whi[idx] = h; Wlo[idx] = l;
    }
}

// ---------------- bf16 MFMA GEMM ----------------
// out fp32 (C, optional blend) or bf16 (Cbf) selected by Cbf != nullptr.
__global__ __launch_bounds__(256)
void mfma_gemm(const float* __restrict__ A, const unsigned short* __restrict__ Wt,
               const float* __restrict__ bias, float* __restrict__ C,
               unsigned short* __restrict__ Cbf,
               const float* __restrict__ Hprev, const float* __restrict__ skipv,
               int M, int N, int K, float a_scale, int blend)
{
    __shared__ unsigned short As[128 * 32];
    __shared__ unsigned short Bs[128 * 32];
    const int bm = blockIdx.x * 128, bn = blockIdx.y * 128;
    const int tid = threadIdx.x;
    const int lane = tid & 63, w = tid >> 6, wr = w >> 1, wc = w & 1;
    const int l16 = lane & 15, lg = lane >> 4;

    v4f acc[4][4] = {};

    const int sr = tid >> 1, sc = (tid & 1) * 16;
    const int arow = bm + sr;
    const bool aok = arow < M;
    const float* ap = A + (size_t)arow * K + sc;
    const unsigned short* bp = Wt + (size_t)(bn + sr) * K + sc;

    const int abase = (wr * 64 + l16) * 32 + lg * 8;
    const int bbase = (wc * 64 + l16) * 32 + lg * 8;

    for (int k0 = 0; k0 < K; k0 += 32) {
        float4 a0 = {0,0,0,0}, a1 = a0, a2 = a0, a3 = a0;
        if (aok) {
            a0 = *(const float4*)(ap + k0);
            a1 = *(const float4*)(ap + k0 + 4);
            a2 = *(const float4*)(ap + k0 + 8);
            a3 = *(const float4*)(ap + k0 + 12);
        }
        uint4 b0 = *(const uint4*)(bp + k0);
        uint4 b1 = *(const uint4*)(bp + k0 + 8);

        if (k0) __syncthreads();

        uint4 w0, w1;
        w0.x = (unsigned int)f2bf(a0.x) | ((unsigned int)f2bf(a0.y) << 16);
        w0.y = (unsigned int)f2bf(a0.z) | ((unsigned int)f2bf(a0.w) << 16);
        w0.z = (unsigned int)f2bf(a1.x) | ((unsigned int)f2bf(a1.y) << 16);
        w0.w = (unsigned int)f2bf(a1.z) | ((unsigned int)f2bf(a1.w) << 16);
        w1.x = (unsigned int)f2bf(a2.x) | ((unsigned int)f2bf(a2.y) << 16);
        w1.y = (unsigned int)f2bf(a2.z) | ((unsigned int)f2bf(a2.w) << 16);
        w1.z = (unsigned int)f2bf(a3.x) | ((unsigned int)f2bf(a3.y) << 16);
        w1.w = (unsigned int)f2bf(a3.z) | ((unsigned int)f2bf(a3.w) << 16);
        *(uint4*)&As[sr * 32 + sc]     = w0;
        *(uint4*)&As[sr * 32 + sc + 8] = w1;
        *(uint4*)&Bs[sr * 32 + sc]     = b0;
        *(uint4*)&Bs[sr * 32 + sc + 8] = b1;
        __syncthreads();

        v8s af[4], bfr[4];
        #pragma unroll
        for (int f = 0; f < 4; ++f) af[f] = *(const v8s*)&As[abase + f * 512];
        #pragma unroll
        for (int f = 0; f < 4; ++f) bfr[f] = *(const v8s*)&Bs[bbase + f * 512];
        #pragma unroll
        for (int i = 0; i < 4; ++i)
            #pragma unroll
            for (int j = 0; j < 4; ++j)
                acc[i][j] = __builtin_amdgcn_mfma_f32_16x16x32_bf16(af[i], bfr[j], acc[i][j], 0, 0, 0);
    }

    float alpha = 1.0f, beta = 0.0f;
    if (blend) {
        float sv = *skipv;
        alpha = 1.0f / (1.0f + expf(-sv));
        beta = 1.0f - alpha;
    }
    const int row0 = bm + wr * 64, col0 = bn + wc * 64;
    float bv[4];
    #pragma unroll
    for (int fn = 0; fn < 4; ++fn) bv[fn] = bias[col0 + fn * 16 + l16];
    #pragma unroll
    for (int fm = 0; fm < 4; ++fm) {
        #pragma unroll
        for (int i = 0; i < 4; ++i) {
            int gm = row0 + fm * 16 + lg * 4 + i;
            if (gm >= M) continue;
            #pragma unroll
            for (int fn = 0; fn < 4; ++fn) {
                int gn = col0 + fn * 16 + l16;
                float val = acc[fm][fn][i] * a_scale + bv[fn];
                if (Cbf) {
                    Cbf[(size_t)gm * N + gn] = f2bf(val);
                } else {
                    if (blend) val = alpha * val + beta * Hprev[(size_t)gm * N + gn];
                    C[(size_t)gm * N + gn] = val;
                }
            }
        }
    }
}

// ---------------- split-precision bf16 MFMA GEMM (final head GEMM) ----------------
// C = A@W + bias with A ~ Ahi+Alo, W ~ Whi+Wlo; computes hi*hi + hi*lo + lo*hi.
__global__ __launch_bounds__(256)
void mfma_gemm_split(const float* __restrict__ A, const unsigned short* __restrict__ Whi,
                     const unsigned short* __restrict__ Wlo, const float* __restrict__ bias,
                     float* __restrict__ C, int M, int N, int K)
{
    __shared__ unsigned short Ah[128 * 32], Al[128 * 32];
    __shared__ unsigned short Bh[128 * 32], Bl[128 * 32];
    const int bm = blockIdx.x * 128, bn = blockIdx.y * 128;
    const int tid = threadIdx.x;
    const int lane = tid & 63, w = tid >> 6, wr = w >> 1, wc = w & 1;
    const int l16 = lane & 15, lg = lane >> 4;

    v4f acc[4][4] = {};

    const int sr = tid >> 1, sc = (tid & 1) * 16;
    const int arow = bm + sr;
    const bool aok = arow < M;
    const float* ap = A + (size_t)arow * K + sc;
    const unsigned short* bhp = Whi + (size_t)(bn + sr) * K + sc;
    const unsigned short* blp = Wlo + (size_t)(bn + sr) * K + sc;

    const int abase = (wr * 64 + l16) * 32 + lg * 8;
    const int bbase = (wc * 64 + l16) * 32 + lg * 8;

    for (int k0 = 0; k0 < K; k0 += 32) {
        float av[16];
        if (aok) {
            *(float4*)&av[0]  = *(const float4*)(ap + k0);
            *(float4*)&av[4]  = *(const float4*)(ap + k0 + 4);
            *(float4*)&av[8]  = *(const float4*)(ap + k0 + 8);
            *(float4*)&av[12] = *(const float4*)(ap + k0 + 12);
        } else {
            #pragma unroll
            for (int u = 0; u < 16; ++u) av[u] = 0.0f;
        }
        uint4 bh0 = *(const uint4*)(bhp + k0);
        uint4 bh1 = *(const uint4*)(bhp + k0 + 8);
        uint4 bl0 = *(const uint4*)(blp + k0);
        uint4 bl1 = *(const uint4*)(blp + k0 + 8);

        if (k0) __syncthreads();

        unsigned int hw[8], lw[8];
        #pragma unroll
        for (int u = 0; u < 8; ++u) {
            unsigned short h0, l0, h1, l1;
            split2(av[2 * u], h0, l0);
            split2(av[2 * u + 1], h1, l1);
            hw[u] = (unsigned int)h0 | ((unsigned int)h1 << 16);
            lw[u] = (unsigned int)l0 | ((unsigned int)l1 << 16);
        }
        *(uint4*)&Ah[sr * 32 + sc]     = *(uint4*)&hw[0];
        *(uint4*)&Ah[sr * 32 + sc + 8] = *(uint4*)&hw[4];
        *(uint4*)&Al[sr * 32 + sc]     = *(uint4*)&lw[0];
        *(uint4*)&Al[sr * 32 + sc + 8] = *(uint4*)&lw[4];
        *(uint4*)&Bh[sr * 32 + sc]     = bh0;
        *(uint4*)&Bh[sr * 32 + sc + 8] = bh1;
        *(uint4*)&Bl[sr * 32 + sc]     = bl0;
        *(uint4*)&Bl[sr * 32 + sc + 8] = bl1;
        __syncthreads();

        v8s ah[4], al[4], bh[4], bl[4];
        #pragma unroll
        for (int f = 0; f < 4; ++f) {
            ah[f] = *(const v8s*)&Ah[abase + f * 512];
            al[f] = *(const v8s*)&Al[abase + f * 512];
            bh[f] = *(const v8s*)&Bh[bbase + f * 512];
            bl[f] = *(const v8s*)&Bl[bbase + f * 512];
        }
        #pragma unroll
        for (int i = 0; i < 4; ++i)
            #pragma unroll
            for (int j = 0; j < 4; ++j) {
                acc[i][j] = __builtin_amdgcn_mfma_f32_16x16x32_bf16(ah[i], bh[j], acc[i][j], 0, 0, 0);
                acc[i][j] = __builtin_amdgcn_mfma_f32_16x16x32_bf16(ah[i], bl[j], acc[i][j], 0, 0, 0);
                acc[i][j] = __builtin_amdgcn_mfma_f32_16x16x32_bf16(al[i], bh[j], acc[i][j], 0, 0, 0);
            }
    }

    const int row0 = bm + wr * 64, col0 = bn + wc * 64;
    float bv[4];
    #pragma unroll
    for (int fn = 0; fn < 4; ++fn) bv[fn] = bias[col0 + fn * 16 + l16];
    #pragma unroll
    for (int fm = 0; fm < 4; ++fm) {
        #pragma unroll
        for (int i = 0; i < 4; ++i) {
            int gm = row0 + fm * 16 + lg * 4 + i;
            if (gm >= M) continue;
            #pragma unroll
            for (int fn = 0; fn < 4; ++fn) {
                int gn = col0 + fn * 16 + l16;
                C[(size_t)gm * N + gn] = acc[fm][fn][i] + bv[fn];
            }
        }
    }
}

// ---------------- CSR build ----------------
__global__ void hist_kernel(const int* __restrict__ dst, int* __restrict__ deg, int E) {
    int e = blockIdx.x * blockDim.x + threadIdx.x;
    if (e < E) atomicAdd(&deg[dst[e]], 1);
}

// single-block shfl-based scan: 6 shfl steps per wave + 2 syncs per 256-chunk
__global__ __launch_bounds__(256)
void scan_kernel(const int* __restrict__ deg, int* __restrict__ rowptr,
                 int* __restrict__ cursor, int nd)
{
    __shared__ int wsum[4];
    const int t = threadIdx.x;
    const int lane = t & 63, w = t >> 6;
    int carry = 0;
    for (int base = 0; base < nd; base += 256) {
        int i = base + t;
        int x = (i < nd) ? deg[i] : 0;
        int inc = x;
        #pragma unroll
        for (int off = 1; off < 64; off <<= 1) {
            int y = __shfl_up(inc, off, 64);
            if (lane >= off) inc += y;
        }
        if (lane == 63) wsum[w] = inc;
        __syncthreads();
        int woff = 0;
        #pragma unroll
        for (int ww = 0; ww < 4; ++ww) if (ww < w) woff += wsum[ww];
        int excl = carry + woff + inc - x;
        if (i < nd) { rowptr[i] = excl; cursor[i] = excl; }
        carry += wsum[0] + wsum[1] + wsum[2] + wsum[3];
        __syncthreads();
    }
    if (t == 0) rowptr[nd] = carry;
}

// scatter + gather src/sim into CSR order (kills one indirection level later)
__global__ void scatter_kernel(const int* __restrict__ dst, const int* __restrict__ src,
                               const float* __restrict__ sim, int* __restrict__ cursor,
                               int* __restrict__ csr_src, float* __restrict__ csr_sim, int E) {
    int e = blockIdx.x * blockDim.x + threadIdx.x;
    if (e < E) {
        int j = atomicAdd(&cursor[dst[e]], 1);
        csr_src[j] = src[e];
        csr_sim[j] = sim[e];
    }
}

// ---------------- fused per-dst-node edge softmax + aggregation (bf16 q/k/v) ----------------
__global__ __launch_bounds__(64)
void node_attn_kernel(const unsigned short* __restrict__ q, const unsigned short* __restrict__ k,
                      const unsigned short* __restrict__ v, const int* __restrict__ rowptr,
                      const int* __restrict__ csr_src, const float* __restrict__ csr_sim,
                      const float* __restrict__ ewp, const float* __restrict__ ebp,
                      float* __restrict__ agg, int accumulate)
{
    const int d = blockIdx.x;
    const int t = threadIdx.x;
    const float ewv = ewp[0], ebv = ebp[0];
    u16x4 q4 = ((const u16x4*)(q + (size_t)d * 256))[t];
    const float qx0 = bf2f(q4[0]), qx1 = bf2f(q4[1]), qx2 = bf2f(q4[2]), qx3 = bf2f(q4[3]);
    const int beg = rowptr[d], end = rowptr[d + 1];

    float m = -INFINITY, s = 0.0f;
    float4 acc = {0.f, 0.f, 0.f, 0.f};

    for (int j = beg; j < end; ++j) {
        int sN = csr_src[j];
        float ea = csr_sim[j] * ewv + ebv;
        u16x4 k4 = ((const u16x4*)(k + (size_t)sN * 256))[t];
        u16x4 v4 = ((const u16x4*)(v + (size_t)sN * 256))[t];
        float dot = qx0 * bf2f(k4[0]) + qx1 * bf2f(k4[1]) + qx2 * bf2f(k4[2]) + qx3 * bf2f(k4[3]);
        dot += __shfl_xor(dot, 1);
        dot += __shfl_xor(dot, 2);
        dot += __shfl_xor(dot, 4);
        float sc = dot * ea * 0.17677669529663687f; // 1/sqrt(32)
        if (sc > m) {
            float r = __expf(m - sc);
            s *= r;
            acc.x *= r; acc.y *= r; acc.z *= r; acc.w *= r;
            m = sc;
        }
        float ex = __expf(sc - m);
        s += ex;
        acc.x += ex * bf2f(v4[0]); acc.y += ex * bf2f(v4[1]);
        acc.z += ex * bf2f(v4[2]); acc.w += ex * bf2f(v4[3]);
    }

    float inv = (end > beg) ? 1.0f / s : 0.0f;
    float4 res = {acc.x * inv, acc.y * inv, acc.z * inv, acc.w * inv};
    float4* outp = (float4*)agg + (size_t)d * 64 + t;
    if (accumulate) {
        float4 old = *outp;
        res.x += old.x; res.y += old.y; res.z += old.z; res.w += old.w;
    }
    *outp = res;
}

__global__ void colsum_kernel(const float* __restrict__ h, float* __restrict__ out, int N)
{
    int c = threadIdx.x;
    float acc = 0.0f;
    for (int r = blockIdx.x; r < N; r += gridDim.x)
        acc += h[(size_t)r * 256 + c];
    atomicAdd(&out[c], acc);
}

__global__ __launch_bounds__(512)
void head_kernel(const float* __restrict__ colsum, float n_img,
                 const float* __restrict__ pred_w, const float* __restrict__ pred_b,
                 const float* __restrict__ head1_w, const float* __restrict__ head1_b,
                 const float* __restrict__ head_w, const float* __restrict__ head_b,
                 float* __restrict__ cvec)
{
    __shared__ float mean[256], o0[256], g[512];
    int t = threadIdx.x;
    if (t < 256) mean[t] = colsum[t] / n_img;
    __syncthreads();
    if (t < 256) {
        float acc = pred_b[t];
        for (int k = 0; k < 256; ++k) acc += mean[k] * pred_w[k * 256 + t];
        o0[t] = acc;
    }
    __syncthreads();
    {
        float acc = head1_b[t];
        for (int k = 0; k < 256; ++k) acc += o0[k] * head1_w[k * 512 + t];
        g[t] = acc;
    }
    __syncthreads();
    {
        float acc = head_b[t];
        for (int k = 0; k < 512; ++k) acc += g[k] * head_w[k * 512 + t];
        cvec[t] = acc;
    }
}

extern "C" void kernel_launch(void* const* d_in, const int* in_sizes, int n_in,
                              void* d_out, int out_size, void* d_ws, size_t ws_size,
                              hipStream_t stream)
{
    const int NI = 20000, NG = 10000, NT = 5000, E = 100000;
    const int ns[3] = {NI, NG, NT};
    const size_t offn[3] = {0, (size_t)NI * 256, (size_t)(NI + NG) * 256};

    const float* feat[3] = {(const float*)d_in[0], (const float*)d_in[1], (const float*)d_in[2]};
    const float* adapt_w = (const float*)d_in[3];
    const float* adapt_b = (const float*)d_in[4];
    const float* k_w = (const float*)d_in[5];
    const float* k_b = (const float*)d_in[6];
    const float* q_w = (const float*)d_in[7];
    const float* q_b = (const float*)d_in[8];
    const float* v_w = (const float*)d_in[9];
    const float* v_b = (const float*)d_in[10];
    const float* a_w = (const float*)d_in[11];
    const float* a_b = (const float*)d_in[12];
    const float* e_w = (const float*)d_in[13];
    const float* e_b = (const float*)d_in[14];
    const float* skip = (const float*)d_in[15];
    const float* pred_w = (const float*)d_in[16];
    const float* pred_b = (const float*)d_in[17];
    const float* head1_w = (const float*)d_in[19];
    const float* head1_b = (const float*)d_in[20];
    const float* head_w = (const float*)d_in[21];
    const float* head_b = (const float*)d_in[22];
    const float* sim[6];
    for (int i = 0; i < 6; ++i) sim[i] = (const float*)d_in[23 + i];
    const int* srcp[6];
    const int* dstp[6];
    for (int i = 0; i < 6; ++i) {
        srcp[i] = (const int*)d_in[29 + 2 * i];
        dstp[i] = (const int*)d_in[30 + 2 * i];
    }
    const int est[6] = {0, 1, 0, 2, 1, 2};
    const int edt[6] = {1, 0, 2, 0, 2, 1};

    float* ws = (float*)d_ws;
    size_t off = 0;
    auto alloc = [&](size_t n) { float* p = ws + off; off += n; return p; };
    const size_t NTOT = (size_t)(NI + NG + NT) * 256;
    float* hb   = alloc(NTOT);
    float* aggb = alloc(NTOT);
    unsigned short* qb = (unsigned short*)alloc(NTOT / 2);
    unsigned short* kb = (unsigned short*)alloc(NTOT / 2);
    unsigned short* vb = (unsigned short*)alloc(NTOT / 2);
    float* csum = alloc(256);
    float* cvec = alloc(512);
    // CSR pools
    int* deg    = (int*)alloc(20001);
    int* cursor = (int*)alloc(20001);
    int* rowptr_[6];
    int* csr_src_[6];
    float* csr_sim_[6];
    for (int i = 0; i < 6; ++i) {
        rowptr_[i]  = (int*)alloc(ns[edt[i]] + 1);
        csr_src_[i] = (int*)alloc(E);
        csr_sim_[i] = alloc(E);
    }
    // bf16 transposed weights
    unsigned short* adapt_wt = (unsigned short*)alloc(3 * 512 * 256 / 2);
    unsigned short* q_wt = (unsigned short*)alloc(6 * 65536 / 2);
    unsigned short* k_wt = (unsigned short*)alloc(6 * 65536 / 2);
    unsigned short* v_wt = (unsigned short*)alloc(6 * 65536 / 2);
    unsigned short* a_wt = (unsigned short*)alloc(6 * 65536 / 2);
    unsigned short* hw_hi = (unsigned short*)alloc(512 * 512 / 2);
    unsigned short* hw_lo = (unsigned short*)alloc(512 * 512 / 2);

    auto gemm_bf = [&](const float* A, const unsigned short* Wt, const float* b,
                       float* C, unsigned short* Cbf, const float* Hp, const float* sk,
                       int M, int N, int K, float asc, int blend) {
        dim3 g((M + 127) / 128, N / 128);
        hipLaunchKernelGGL(mfma_gemm, g, dim3(256), 0, stream,
                           A, Wt, b, C, Cbf, Hp, sk, M, N, K, asc, blend);
    };

    // ---- build CSR per etype (reused by both layers) ----
    for (int i = 0; i < 6; ++i) {
        int nd = ns[edt[i]];
        hipMemsetAsync(deg, 0, (size_t)nd * sizeof(int), stream);
        hipLaunchKernelGGL(hist_kernel, dim3((E + 255) / 256), dim3(256), 0, stream,
                           dstp[i], deg, E);
        hipLaunchKernelGGL(scan_kernel, dim3(1), dim3(256), 0, stream,
                           deg, rowptr_[i], cursor, nd);
        hipLaunchKernelGGL(scatter_kernel, dim3((E + 255) / 256), dim3(256), 0, stream,
                           dstp[i], srcp[i], sim[i], cursor, csr_src_[i], csr_sim_[i], E);
    }

    // ---- weights -> bf16 W^T (and split for head_w) ----
    hipLaunchKernelGGL(wcvt_kernel, dim3(16, 8, 3), dim3(256), 0, stream, adapt_w, adapt_wt, 512, 256);
    hipLaunchKernelGGL(wcvt_kernel, dim3(8, 8, 6), dim3(256), 0, stream, q_w, q_wt, 256, 256);
    hipLaunchKernelGGL(wcvt_kernel, dim3(8, 8, 6), dim3(256), 0, stream, k_w, k_wt, 256, 256);
    hipLaunchKernelGGL(wcvt_kernel, dim3(8, 8, 6), dim3(256), 0, stream, v_w, v_wt, 256, 256);
    hipLaunchKernelGGL(wcvt_kernel, dim3(8, 8, 6), dim3(256), 0, stream, a_w, a_wt, 256, 256);
    hipLaunchKernelGGL(wcvt_split_kernel, dim3(16, 16), dim3(256), 0, stream, head_w, hw_hi, hw_lo, 512, 512);

    // adapt: h[t] = feats[t] @ adapt_w[t] + adapt_b[t]  (fp32 out)
    for (int t = 0; t < 3; ++t)
        gemm_bf(feat[t], adapt_wt + (size_t)t * 512 * 256, adapt_b + t * 256,
                hb + offn[t], nullptr, nullptr, nullptr, ns[t], 256, 512, 1.0f, 0);

    for (int l = 0; l < 2; ++l) {
        for (int t = 0; t < 3; ++t) {
            size_t wo = ((size_t)l * 3 + t) * 65536, bo = ((size_t)l * 3 + t) * 256;
            gemm_bf(hb + offn[t], q_wt + wo, q_b + bo, nullptr, qb + offn[t], nullptr, nullptr, ns[t], 256, 256, 1.0f, 0);
            gemm_bf(hb + offn[t], k_wt + wo, k_b + bo, nullptr, kb + offn[t], nullptr, nullptr, ns[t], 256, 256, 1.0f, 0);
            gemm_bf(hb + offn[t], v_wt + wo, v_b + bo, nullptr, vb + offn[t], nullptr, nullptr, ns[t], 256, 256, 1.0f, 0);
        }
        for (int i = 0; i < 6; ++i) {
            int st = est[i], dt = edt[i];
            hipLaunchKernelGGL(node_attn_kernel, dim3(ns[dt]), dim3(64), 0, stream,
                               qb + offn[dt], kb + offn[st], vb + offn[st],
                               rowptr_[i], csr_src_[i], csr_sim_[i],
                               e_w + l, e_b + l, aggb + offn[dt], (i >= 3) ? 1 : 0);
        }
        for (int t = 0; t < 3; ++t) {
            size_t wo = ((size_t)l * 3 + t) * 65536, bo = ((size_t)l * 3 + t) * 256;
            gemm_bf(aggb + offn[t], a_wt + wo, a_b + bo, hb + offn[t], nullptr,
                    hb + offn[t], skip + l * 3 + t, ns[t], 256, 256, 0.5f, 1);
        }
    }

    hipMemsetAsync(csum, 0, 256 * sizeof(float), stream);
    hipLaunchKernelGGL(colsum_kernel, dim3(128), dim3(256), 0, stream, hb, csum, NI);
    hipLaunchKernelGGL(head_kernel, dim3(1), dim3(512), 0, stream,
                       csum, (float)NI, pred_w, pred_b, head1_w, head1_b, head_w, head_b, cvec);

    // out = feats[0] @ head_w + cvec  (split-bf16 MFMA, ~2^-17 representation error)
    {
        dim3 g((NI + 127) / 128, 512 / 128);
        hipLaunchKernelGGL(mfma_gemm_split, g, dim3(256), 0, stream,
                           feat[0], hw_hi, hw_lo, cvec, (float*)d_out, NI, 512, 512);
    }
}

// Round 5
// 606.716 us; speedup vs baseline: 5.2046x; 1.9509x over previous
//
#include <hip/hip_runtime.h>
#include <hip/hip_bf16.h>
#include <math.h>

typedef short v8s __attribute__((ext_vector_type(8)));
typedef float v4f __attribute__((ext_vector_type(4)));
typedef unsigned short u16x4 __attribute__((ext_vector_type(4)));

__device__ __forceinline__ unsigned short f2bf(float f) {
    unsigned int u = __float_as_uint(f);
    u += 0x7fff + ((u >> 16) & 1);   // round-to-nearest-even
    return (unsigned short)(u >> 16);
}
__device__ __forceinline__ float bf2f(unsigned short h) {
    return __uint_as_float(((unsigned int)h) << 16);
}
__device__ __forceinline__ void split2(float f, unsigned short& h, unsigned short& l) {
    h = f2bf(f);
    float r = f - bf2f(h);      // exact
    l = f2bf(r);
}

struct GraphPtrs { const int* dst[6]; const int* src[6]; const float* sim[6]; };
struct Ptr3f { const float* p[3]; };

// etype geometry (compile-time): dst-type per etype {1,0,2,0,2,1}
// nd per etype: {10000,20000,5000,20000,5000,10000}

// ---------------- weight transpose + convert: W[K][N] fp32 -> Wt[N][K] bf16 ----------------
__global__ __launch_bounds__(256)
void wcvt_kernel(const float* __restrict__ W, unsigned short* __restrict__ Wt, int K, int N)
{
    __shared__ float tile[32][33];
    const int b = blockIdx.z;
    const float* Wb = W + (size_t)b * K * N;
    unsigned short* Wtb = Wt + (size_t)b * K * N;
    const int k0 = blockIdx.x * 32, n0 = blockIdx.y * 32;
    const int x = threadIdx.x & 31, y = threadIdx.x >> 5;
    #pragma unroll
    for (int j = 0; j < 4; ++j)
        tile[y + 8 * j][x] = Wb[(size_t)(k0 + y + 8 * j) * N + n0 + x];
    __syncthreads();
    #pragma unroll
    for (int j = 0; j < 4; ++j)
        Wtb[(size_t)(n0 + y + 8 * j) * K + k0 + x] = f2bf(tile[x][y + 8 * j]);
}

// q/k/v weights -> W3[(l,t)][768][256] (rows 0-255 q, 256-511 k, 512-767 v)
__global__ __launch_bounds__(256)
void wcvt_qkv_kernel(const float* __restrict__ qw, const float* __restrict__ kw,
                     const float* __restrict__ vw, unsigned short* __restrict__ W3)
{
    __shared__ float tile[32][33];
    const int z = blockIdx.z, lt = z / 3, sec = z - lt * 3;
    const float* src = (sec == 0 ? qw : sec == 1 ? kw : vw) + (size_t)lt * 65536;
    unsigned short* dst = W3 + ((size_t)lt * 768 + sec * 256) * 256;
    const int k0 = blockIdx.x * 32, n0 = blockIdx.y * 32;
    const int x = threadIdx.x & 31, y = threadIdx.x >> 5;
    #pragma unroll
    for (int j = 0; j < 4; ++j)
        tile[y + 8 * j][x] = src[(size_t)(k0 + y + 8 * j) * 256 + n0 + x];
    __syncthreads();
    #pragma unroll
    for (int j = 0; j < 4; ++j)
        dst[(size_t)(n0 + y + 8 * j) * 256 + k0 + x] = f2bf(tile[x][y + 8 * j]);
}

// hi/lo split transpose for the final head GEMM
__global__ __launch_bounds__(256)
void wcvt_split_kernel(const float* __restrict__ W, unsigned short* __restrict__ Whi,
                       unsigned short* __restrict__ Wlo, int K, int N)
{
    __shared__ float tile[32][33];
    const int k0 = blockIdx.x * 32, n0 = blockIdx.y * 32;
    const int x = threadIdx.x & 31, y = threadIdx.x >> 5;
    #pragma unroll
    for (int j = 0; j < 4; ++j)
        tile[y + 8 * j][x] = W[(size_t)(k0 + y + 8 * j) * N + n0 + x];
    __syncthreads();
    #pragma unroll
    for (int j = 0; j < 4; ++j) {
        unsigned short h, l;
        split2(tile[x][y + 8 * j], h, l);
        size_t idx = (size_t)(n0 + y + 8 * j) * K + k0 + x;
        Whi[idx] = h; Wlo[idx] = l;
    }
}

// bias768[lt][768] = concat(q_b[lt], k_b[lt], v_b[lt])
__global__ void bias_concat_kernel(const float* __restrict__ qb, const float* __restrict__ kb,
                                   const float* __restrict__ vb, float* __restrict__ out)
{
    int i = blockIdx.x * 256 + threadIdx.x;
    if (i < 6 * 768) {
        int lt = i / 768, c = i - lt * 768;
        int sec = c >> 8, cc = c & 255;
        const float* s = sec == 0 ? qb : sec == 1 ? kb : vb;
        out[i] = s[lt * 256 + cc];
    }
}

// ---------------- CSR build (all 6 etypes fused) ----------------
__global__ void hist6_kernel(GraphPtrs gp, int* __restrict__ deg6)
{
    constexpr int doff[6] = {0, 10000, 30000, 35000, 55000, 60000};
    const int ei = blockIdx.y;
    int e = blockIdx.x * 256 + threadIdx.x;
    if (e < 100000) atomicAdd(&deg6[doff[ei] + gp.dst[ei][e]], 1);
}

__global__ __launch_bounds__(256)
void scan6_kernel(const int* __restrict__ deg6, int* __restrict__ rp6, int* __restrict__ cursor6)
{
    constexpr int ndv[6]   = {10000, 20000, 5000, 20000, 5000, 10000};
    constexpr int doff[6]  = {0, 10000, 30000, 35000, 55000, 60000};
    constexpr int rpoff[6] = {0, 10001, 30002, 35003, 55004, 60005};
    const int b = blockIdx.x;
    const int nd = ndv[b];
    const int* deg = deg6 + doff[b];
    int* rowptr = rp6 + rpoff[b];
    int* cursor = cursor6 + doff[b];
    const int t = threadIdx.x, lane = t & 63, w = t >> 6;
    __shared__ int wsum[4];
    int carry = 0;
    for (int base = 0; base < nd; base += 1024) {
        int i0 = base + t * 4;
        int x0 = 0, x1 = 0, x2 = 0, x3 = 0;
        if (i0 + 3 < nd) {
            int4 v = *(const int4*)(deg + i0);
            x0 = v.x; x1 = v.y; x2 = v.z; x3 = v.w;
        } else {
            if (i0 < nd) x0 = deg[i0];
            if (i0 + 1 < nd) x1 = deg[i0 + 1];
            if (i0 + 2 < nd) x2 = deg[i0 + 2];
            if (i0 + 3 < nd) x3 = deg[i0 + 3];
        }
        int s1 = x0 + x1, s2 = s1 + x2, tot = s2 + x3;
        int inc = tot;
        #pragma unroll
        for (int o = 1; o < 64; o <<= 1) {
            int y = __shfl_up(inc, o, 64);
            if (lane >= o) inc += y;
        }
        if (lane == 63) wsum[w] = inc;
        __syncthreads();
        int woff = 0;
        #pragma unroll
        for (int ww = 0; ww < 4; ++ww) if (ww < w) woff += wsum[ww];
        int ebase = carry + woff + inc - tot;
        if (i0 < nd)     { rowptr[i0] = ebase;          cursor[i0] = ebase; }
        if (i0 + 1 < nd) { rowptr[i0 + 1] = ebase + x0; cursor[i0 + 1] = ebase + x0; }
        if (i0 + 2 < nd) { rowptr[i0 + 2] = ebase + s1; cursor[i0 + 2] = ebase + s1; }
        if (i0 + 3 < nd) { rowptr[i0 + 3] = ebase + s2; cursor[i0 + 3] = ebase + s2; }
        carry += wsum[0] + wsum[1] + wsum[2] + wsum[3];
        __syncthreads();
    }
    if (t == 0) rowptr[nd] = carry;
}

__global__ void scatter6_kernel(GraphPtrs gp, int* __restrict__ cursor6,
                                int* __restrict__ csr_src6, float* __restrict__ csr_sim6)
{
    constexpr int doff[6] = {0, 10000, 30000, 35000, 55000, 60000};
    const int ei = blockIdx.y;
    int e = blockIdx.x * 256 + threadIdx.x;
    if (e < 100000) {
        int j = atomicAdd(&cursor6[doff[ei] + gp.dst[ei][e]], 1);
        csr_src6[(size_t)ei * 100000 + j] = gp.src[ei][e];
        csr_sim6[(size_t)ei * 100000 + j] = gp.sim[ei][e];
    }
}

// ---------------- shared MFMA GEMM core (128x128 tile, BK=32) ----------------
__device__ __forceinline__ void gemm_core(const float* __restrict__ A,
    const unsigned short* __restrict__ Wt, int M, int K, int bm, int bn,
    unsigned short* __restrict__ As, unsigned short* __restrict__ Bs, v4f acc[4][4])
{
    const int tid = threadIdx.x;
    const int sr = tid >> 1, sc = (tid & 1) * 16;
    const int arow = bm + sr;
    const bool aok = arow < M;
    const float* ap = A + (size_t)arow * K + sc;
    const unsigned short* bp = Wt + (size_t)(bn + sr) * K + sc;
    const int lane = tid & 63, w = tid >> 6, wr = w >> 1, wc = w & 1;
    const int l16 = lane & 15, lg = lane >> 4;
    const int abase = (wr * 64 + l16) * 32 + lg * 8;
    const int bbase = (wc * 64 + l16) * 32 + lg * 8;

    for (int k0 = 0; k0 < K; k0 += 32) {
        float4 a0 = {0,0,0,0}, a1 = a0, a2 = a0, a3 = a0;
        if (aok) {
            a0 = *(const float4*)(ap + k0);
            a1 = *(const float4*)(ap + k0 + 4);
            a2 = *(const float4*)(ap + k0 + 8);
            a3 = *(const float4*)(ap + k0 + 12);
        }
        uint4 b0 = *(const uint4*)(bp + k0);
        uint4 b1 = *(const uint4*)(bp + k0 + 8);

        if (k0) __syncthreads();

        uint4 w0, w1;
        w0.x = (unsigned int)f2bf(a0.x) | ((unsigned int)f2bf(a0.y) << 16);
        w0.y = (unsigned int)f2bf(a0.z) | ((unsigned int)f2bf(a0.w) << 16);
        w0.z = (unsigned int)f2bf(a1.x) | ((unsigned int)f2bf(a1.y) << 16);
        w0.w = (unsigned int)f2bf(a1.z) | ((unsigned int)f2bf(a1.w) << 16);
        w1.x = (unsigned int)f2bf(a2.x) | ((unsigned int)f2bf(a2.y) << 16);
        w1.y = (unsigned int)f2bf(a2.z) | ((unsigned int)f2bf(a2.w) << 16);
        w1.z = (unsigned int)f2bf(a3.x) | ((unsigned int)f2bf(a3.y) << 16);
        w1.w = (unsigned int)f2bf(a3.z) | ((unsigned int)f2bf(a3.w) << 16);
        *(uint4*)&As[sr * 32 + sc]     = w0;
        *(uint4*)&As[sr * 32 + sc + 8] = w1;
        *(uint4*)&Bs[sr * 32 + sc]     = b0;
        *(uint4*)&Bs[sr * 32 + sc + 8] = b1;
        __syncthreads();

        v8s af[4], bfr[4];
        #pragma unroll
        for (int f = 0; f < 4; ++f) af[f] = *(const v8s*)&As[abase + f * 512];
        #pragma unroll
        for (int f = 0; f < 4; ++f) bfr[f] = *(const v8s*)&Bs[bbase + f * 512];
        #pragma unroll
        for (int i = 0; i < 4; ++i)
            #pragma unroll
            for (int j = 0; j < 4; ++j)
                acc[i][j] = __builtin_amdgcn_mfma_f32_16x16x32_bf16(af[i], bfr[j], acc[i][j], 0, 0, 0);
    }
}

// ---- adapt: h[t] = feats[t] @ adapt_w[t] + adapt_b[t]  (3 types fused via z) ----
__global__ __launch_bounds__(256)
void adapt_gemm3(Ptr3f A3, const unsigned short* __restrict__ Wt3,
                 const float* __restrict__ bias3, float* __restrict__ hb)
{
    constexpr int Ms[3] = {20000, 10000, 5000};
    constexpr size_t hoff[3] = {0, 20000ull * 256, 30000ull * 256};
    const int z = blockIdx.z;
    const int M = Ms[z];
    const int bm = blockIdx.y * 128, bn = blockIdx.x * 128;
    if (bm >= M) return;
    __shared__ unsigned short As[128 * 32], Bs[128 * 32];
    v4f acc[4][4] = {};
    gemm_core(A3.p[z], Wt3 + (size_t)z * 256 * 512, M, 512, bm, bn, As, Bs, acc);

    const int lane = threadIdx.x & 63, w = threadIdx.x >> 6;
    const int wr = w >> 1, wc = w & 1, l16 = lane & 15, lg = lane >> 4;
    const int row0 = bm + wr * 64, col0 = bn + wc * 64;
    const float* bias = bias3 + z * 256;
    float* C = hb + hoff[z];
    float bv[4];
    #pragma unroll
    for (int fn = 0; fn < 4; ++fn) bv[fn] = bias[col0 + fn * 16 + l16];
    #pragma unroll
    for (int fm = 0; fm < 4; ++fm)
        #pragma unroll
        for (int i = 0; i < 4; ++i) {
            int gm = row0 + fm * 16 + lg * 4 + i;
            if (gm >= M) continue;
            #pragma unroll
            for (int fn = 0; fn < 4; ++fn)
                C[(size_t)gm * 256 + col0 + fn * 16 + l16] = acc[fm][fn][i] + bv[fn];
        }
}

// ---- qkv: qkv[t][node][768] bf16 = h[t] @ W3[l,t] + bias768[l,t]  (3 types fused) ----
__global__ __launch_bounds__(256)
void qkv_gemm3(const float* __restrict__ hb, const unsigned short* __restrict__ W3l,
               const float* __restrict__ bias768l, unsigned short* __restrict__ qkvb)
{
    constexpr int Ms[3] = {20000, 10000, 5000};
    constexpr size_t hoff[3] = {0, 20000ull * 256, 30000ull * 256};
    constexpr size_t qoff[3] = {0, 20000ull * 768, 30000ull * 768};
    const int z = blockIdx.z;
    const int M = Ms[z];
    const int bm = blockIdx.y * 128, bn = blockIdx.x * 128;
    if (bm >= M) return;
    __shared__ unsigned short As[128 * 32], Bs[128 * 32];
    v4f acc[4][4] = {};
    gemm_core(hb + hoff[z], W3l + (size_t)z * 768 * 256, M, 256, bm, bn, As, Bs, acc);

    const int lane = threadIdx.x & 63, w = threadIdx.x >> 6;
    const int wr = w >> 1, wc = w & 1, l16 = lane & 15, lg = lane >> 4;
    const int row0 = bm + wr * 64, col0 = bn + wc * 64;
    const float* bias = bias768l + z * 768;
    unsigned short* C = qkvb + qoff[z];
    float bv[4];
    #pragma unroll
    for (int fn = 0; fn < 4; ++fn) bv[fn] = bias[col0 + fn * 16 + l16];
    #pragma unroll
    for (int fm = 0; fm < 4; ++fm)
        #pragma unroll
        for (int i = 0; i < 4; ++i) {
            int gm = row0 + fm * 16 + lg * 4 + i;
            if (gm >= M) continue;
            #pragma unroll
            for (int fn = 0; fn < 4; ++fn)
                C[(size_t)gm * 768 + col0 + fn * 16 + l16] = f2bf(acc[fm][fn][i] + bv[fn]);
        }
}

// ---- a: h[t] = blend(0.5*agg[t]@a_w[l,t] + a_b[l,t], h[t])  (3 types fused) ----
__global__ __launch_bounds__(256)
void a_gemm3(const float* __restrict__ aggb, const unsigned short* __restrict__ Wtl,
             const float* __restrict__ biasl, const float* __restrict__ skipl,
             float* __restrict__ hb)
{
    constexpr int Ms[3] = {20000, 10000, 5000};
    constexpr size_t hoff[3] = {0, 20000ull * 256, 30000ull * 256};
    const int z = blockIdx.z;
    const int M = Ms[z];
    const int bm = blockIdx.y * 128, bn = blockIdx.x * 128;
    if (bm >= M) return;
    __shared__ unsigned short As[128 * 32], Bs[128 * 32];
    v4f acc[4][4] = {};
    gemm_core(aggb + hoff[z], Wtl + (size_t)z * 65536, M, 256, bm, bn, As, Bs, acc);

    const int lane = threadIdx.x & 63, w = threadIdx.x >> 6;
    const int wr = w >> 1, wc = w & 1, l16 = lane & 15, lg = lane >> 4;
    const int row0 = bm + wr * 64, col0 = bn + wc * 64;
    const float* bias = biasl + z * 256;
    float* C = hb + hoff[z];
    float sv = skipl[z];
    float alpha = 1.0f / (1.0f + expf(-sv));
    float beta = 1.0f - alpha;
    float bv[4];
    #pragma unroll
    for (int fn = 0; fn < 4; ++fn) bv[fn] = bias[col0 + fn * 16 + l16];
    #pragma unroll
    for (int fm = 0; fm < 4; ++fm)
        #pragma unroll
        for (int i = 0; i < 4; ++i) {
            int gm = row0 + fm * 16 + lg * 4 + i;
            if (gm >= M) continue;
            #pragma unroll
            for (int fn = 0; fn < 4; ++fn) {
                size_t idx = (size_t)gm * 256 + col0 + fn * 16 + l16;
                float val = acc[fm][fn][i] * 0.5f + bv[fn];
                C[idx] = alpha * val + beta * C[idx];
            }
        }
}

// ---------------- split-precision bf16 MFMA GEMM (final head GEMM) ----------------
__global__ __launch_bounds__(256)
void mfma_gemm_split(const float* __restrict__ A, const unsigned short* __restrict__ Whi,
                     const unsigned short* __restrict__ Wlo, const float* __restrict__ bias,
                     float* __restrict__ C, int M, int N, int K)
{
    __shared__ unsigned short Ah[128 * 32], Al[128 * 32];
    __shared__ unsigned short Bh[128 * 32], Bl[128 * 32];
    const int bm = blockIdx.y * 128, bn = blockIdx.x * 128;
    if (bm >= M) return;
    const int tid = threadIdx.x;
    const int lane = tid & 63, w = tid >> 6, wr = w >> 1, wc = w & 1;
    const int l16 = lane & 15, lg = lane >> 4;

    v4f acc[4][4] = {};

    const int sr = tid >> 1, sc = (tid & 1) * 16;
    const int arow = bm + sr;
    const bool aok = arow < M;
    const float* ap = A + (size_t)arow * K + sc;
    const unsigned short* bhp = Whi + (size_t)(bn + sr) * K + sc;
    const unsigned short* blp = Wlo + (size_t)(bn + sr) * K + sc;

    const int abase = (wr * 64 + l16) * 32 + lg * 8;
    const int bbase = (wc * 64 + l16) * 32 + lg * 8;

    for (int k0 = 0; k0 < K; k0 += 32) {
        float av[16];
        if (aok) {
            *(float4*)&av[0]  = *(const float4*)(ap + k0);
            *(float4*)&av[4]  = *(const float4*)(ap + k0 + 4);
            *(float4*)&av[8]  = *(const float4*)(ap + k0 + 8);
            *(float4*)&av[12] = *(const float4*)(ap + k0 + 12);
        } else {
            #pragma unroll
            for (int u = 0; u < 16; ++u) av[u] = 0.0f;
        }
        uint4 bh0 = *(const uint4*)(bhp + k0);
        uint4 bh1 = *(const uint4*)(bhp + k0 + 8);
        uint4 bl0 = *(const uint4*)(blp + k0);
        uint4 bl1 = *(const uint4*)(blp + k0 + 8);

        if (k0) __syncthreads();

        unsigned int hw[8], lw[8];
        #pragma unroll
        for (int u = 0; u < 8; ++u) {
            unsigned short h0, l0, h1, l1;
            split2(av[2 * u], h0, l0);
            split2(av[2 * u + 1], h1, l1);
            hw[u] = (unsigned int)h0 | ((unsigned int)h1 << 16);
            lw[u] = (unsigned int)l0 | ((unsigned int)l1 << 16);
        }
        *(uint4*)&Ah[sr * 32 + sc]     = *(uint4*)&hw[0];
        *(uint4*)&Ah[sr * 32 + sc + 8] = *(uint4*)&hw[4];
        *(uint4*)&Al[sr * 32 + sc]     = *(uint4*)&lw[0];
        *(uint4*)&Al[sr * 32 + sc + 8] = *(uint4*)&lw[4];
        *(uint4*)&Bh[sr * 32 + sc]     = bh0;
        *(uint4*)&Bh[sr * 32 + sc + 8] = bh1;
        *(uint4*)&Bl[sr * 32 + sc]     = bl0;
        *(uint4*)&Bl[sr * 32 + sc + 8] = bl1;
        __syncthreads();

        v8s ah[4], al[4], bh[4], bl[4];
        #pragma unroll
        for (int f = 0; f < 4; ++f) {
            ah[f] = *(const v8s*)&Ah[abase + f * 512];
            al[f] = *(const v8s*)&Al[abase + f * 512];
            bh[f] = *(const v8s*)&Bh[bbase + f * 512];
            bl[f] = *(const v8s*)&Bl[bbase + f * 512];
        }
        #pragma unroll
        for (int i = 0; i < 4; ++i)
            #pragma unroll
            for (int j = 0; j < 4; ++j) {
                acc[i][j] = __builtin_amdgcn_mfma_f32_16x16x32_bf16(ah[i], bh[j], acc[i][j], 0, 0, 0);
                acc[i][j] = __builtin_amdgcn_mfma_f32_16x16x32_bf16(ah[i], bl[j], acc[i][j], 0, 0, 0);
                acc[i][j] = __builtin_amdgcn_mfma_f32_16x16x32_bf16(al[i], bh[j], acc[i][j], 0, 0, 0);
            }
    }

    const int row0 = bm + wr * 64, col0 = bn + wc * 64;
    float bv[4];
    #pragma unroll
    for (int fn = 0; fn < 4; ++fn) bv[fn] = bias[col0 + fn * 16 + l16];
    #pragma unroll
    for (int fm = 0; fm < 4; ++fm)
        #pragma unroll
        for (int i = 0; i < 4; ++i) {
            int gm = row0 + fm * 16 + lg * 4 + i;
            if (gm >= M) continue;
            #pragma unroll
            for (int fn = 0; fn < 4; ++fn)
                C[(size_t)gm * N + col0 + fn * 16 + l16] = acc[fm][fn][i] + bv[fn];
        }
}

// ---------------- fused attention: all 3 dst types, both relations, one dispatch ----------------
__global__ __launch_bounds__(256)
void attn_fused_kernel(const unsigned short* __restrict__ qkvb,
                       const int* __restrict__ rp6, const int* __restrict__ csr_src6,
                       const float* __restrict__ csr_sim6,
                       const float* __restrict__ ewp, const float* __restrict__ ebp,
                       float* __restrict__ aggb)
{
    constexpr int ndd[3] = {20000, 10000, 5000};
    constexpr size_t qoff[3] = {0, 20000ull * 768, 30000ull * 768};
    constexpr size_t aoff[3] = {0, 20000ull * 256, 30000ull * 256};
    constexpr int rpoff[6] = {0, 10001, 30002, 35003, 55004, 60005};
    constexpr int eA[3] = {1, 0, 2}, eB[3] = {3, 5, 4};      // incoming etypes per dst type
    constexpr int sA[3] = {1, 0, 0}, sB[3] = {2, 2, 1};      // their src node types

    const int z = blockIdx.y;
    const int d = blockIdx.x * 4 + (threadIdx.x >> 6);
    if (d >= ndd[z]) return;
    const int t = threadIdx.x & 63;
    const float ewv = ewp[0], ebv = ebp[0];

    u16x4 q4 = *(const u16x4*)(qkvb + qoff[z] + (size_t)d * 768 + 4 * t);
    const float qx0 = bf2f(q4[0]), qx1 = bf2f(q4[1]), qx2 = bf2f(q4[2]), qx3 = bf2f(q4[3]);

    float4 res = {0.f, 0.f, 0.f, 0.f};
    #pragma unroll
    for (int r = 0; r < 2; ++r) {
        const int ei = r == 0 ? eA[z] : eB[z];
        const int stp = r == 0 ? sA[z] : sB[z];
        const int* rowptr = rp6 + rpoff[ei];
        const int* csrc = csr_src6 + (size_t)ei * 100000;
        const float* csim = csr_sim6 + (size_t)ei * 100000;
        const unsigned short* kvb = qkvb + qoff[stp];
        const int beg = rowptr[d], end = rowptr[d + 1];

        float m = -INFINITY, s = 0.0f;
        float4 acc = {0.f, 0.f, 0.f, 0.f};

        // 2-stage pipeline: prefetch next edge's k/v while computing current
        u16x4 k4n = {0,0,0,0}, v4n = {0,0,0,0};
        float simn = 0.0f;
        if (beg < end) {
            int sN = csrc[beg];
            simn = csim[beg];
            const unsigned short* kr = kvb + (size_t)sN * 768 + 4 * t;
            k4n = *(const u16x4*)(kr + 256);
            v4n = *(const u16x4*)(kr + 512);
        }
        for (int j = beg; j < end; ++j) {
            u16x4 k4 = k4n, v4 = v4n;
            float simv = simn;
            if (j + 1 < end) {
                int sN = csrc[j + 1];
                simn = csim[j + 1];
                const unsigned short* kr = kvb + (size_t)sN * 768 + 4 * t;
                k4n = *(const u16x4*)(kr + 256);
                v4n = *(const u16x4*)(kr + 512);
            }
            float dot = qx0 * bf2f(k4[0]) + qx1 * bf2f(k4[1]) + qx2 * bf2f(k4[2]) + qx3 * bf2f(k4[3]);
            dot += __shfl_xor(dot, 1);
            dot += __shfl_xor(dot, 2);
            dot += __shfl_xor(dot, 4);
            float sc = dot * (simv * ewv + ebv) * 0.17677669529663687f;  // 1/sqrt(32)
            if (sc > m) {
                float rr = __expf(m - sc);
                s *= rr;
                acc.x *= rr; acc.y *= rr; acc.z *= rr; acc.w *= rr;
                m = sc;
            }
            float ex = __expf(sc - m);
            s += ex;
            acc.x += ex * bf2f(v4[0]); acc.y += ex * bf2f(v4[1]);
            acc.z += ex * bf2f(v4[2]); acc.w += ex * bf2f(v4[3]);
        }
        float inv = (end > beg) ? 1.0f / s : 0.0f;
        res.x += acc.x * inv; res.y += acc.y * inv;
        res.z += acc.z * inv; res.w += acc.w * inv;
    }
    *((float4*)(aggb + aoff[z]) + (size_t)d * 64 + t) = res;
}

__global__ void colsum_kernel(const float* __restrict__ h, float* __restrict__ out, int N)
{
    int c = threadIdx.x;
    float acc = 0.0f;
    for (int r = blockIdx.x; r < N; r += gridDim.x)
        acc += h[(size_t)r * 256 + c];
    atomicAdd(&out[c], acc);
}

__global__ __launch_bounds__(512)
void head_kernel(const float* __restrict__ colsum, float n_img,
                 const float* __restrict__ pred_w, const float* __restrict__ pred_b,
                 const float* __restrict__ head1_w, const float* __restrict__ head1_b,
                 const float* __restrict__ head_w, const float* __restrict__ head_b,
                 float* __restrict__ cvec)
{
    __shared__ float mean[256], o0[256], g[512];
    int t = threadIdx.x;
    if (t < 256) mean[t] = colsum[t] / n_img;
    __syncthreads();
    if (t < 256) {
        float acc = pred_b[t];
        for (int k = 0; k < 256; ++k) acc += mean[k] * pred_w[k * 256 + t];
        o0[t] = acc;
    }
    __syncthreads();
    {
        float acc = head1_b[t];
        for (int k = 0; k < 256; ++k) acc += o0[k] * head1_w[k * 512 + t];
        g[t] = acc;
    }
    __syncthreads();
    {
        float acc = head_b[t];
        for (int k = 0; k < 512; ++k) acc += g[k] * head_w[k * 512 + t];
        cvec[t] = acc;
    }
}

extern "C" void kernel_launch(void* const* d_in, const int* in_sizes, int n_in,
                              void* d_out, int out_size, void* d_ws, size_t ws_size,
                              hipStream_t stream)
{
    const int NI = 20000, E = 100000;

    const float* feat[3] = {(const float*)d_in[0], (const float*)d_in[1], (const float*)d_in[2]};
    const float* adapt_w = (const float*)d_in[3];
    const float* adapt_b = (const float*)d_in[4];
    const float* k_w = (const float*)d_in[5];
    const float* k_b = (const float*)d_in[6];
    const float* q_w = (const float*)d_in[7];
    const float* q_b = (const float*)d_in[8];
    const float* v_w = (const float*)d_in[9];
    const float* v_b = (const float*)d_in[10];
    const float* a_w = (const float*)d_in[11];
    const float* a_b = (const float*)d_in[12];
    const float* e_w = (const float*)d_in[13];
    const float* e_b = (const float*)d_in[14];
    const float* skip = (const float*)d_in[15];
    const float* pred_w = (const float*)d_in[16];
    const float* pred_b = (const float*)d_in[17];
    const float* head1_w = (const float*)d_in[19];
    const float* head1_b = (const float*)d_in[20];
    const float* head_w = (const float*)d_in[21];
    const float* head_b = (const float*)d_in[22];

    GraphPtrs gp;
    for (int i = 0; i < 6; ++i) {
        gp.sim[i] = (const float*)d_in[23 + i];
        gp.src[i] = (const int*)d_in[29 + 2 * i];
        gp.dst[i] = (const int*)d_in[30 + 2 * i];
    }

    float* ws = (float*)d_ws;
    size_t off = 0;
    auto alloc = [&](size_t n) { float* p = ws + off; off += (n + 3) & ~(size_t)3; return p; };
    const size_t NTOT = 35000ull * 256;
    float* hb   = alloc(NTOT);
    float* aggb = alloc(NTOT);
    unsigned short* qkvb = (unsigned short*)alloc(NTOT * 3 / 2);   // [node][768] bf16
    float* csum = alloc(256);
    float* cvec = alloc(512);
    int* deg6    = (int*)alloc(70000);
    int* cursor6 = (int*)alloc(70000);
    int* rp6     = (int*)alloc(70012);
    int* csr_src6   = (int*)alloc(600000);
    float* csr_sim6 = alloc(600000);
    unsigned short* adapt_wt = (unsigned short*)alloc(3 * 512 * 256 / 2);
    unsigned short* W3   = (unsigned short*)alloc(6ull * 768 * 256 / 2);  // [lt][768][256]
    unsigned short* a_wt = (unsigned short*)alloc(6 * 65536 / 2);
    float* bias768 = alloc(6 * 768);
    unsigned short* hw_hi = (unsigned short*)alloc(512 * 512 / 2);
    unsigned short* hw_lo = (unsigned short*)alloc(512 * 512 / 2);

    // ---- CSR build: 4 dispatches for all 6 etypes ----
    hipMemsetAsync(deg6, 0, 70000 * sizeof(int), stream);
    hipLaunchKernelGGL(hist6_kernel, dim3((E + 255) / 256, 6), dim3(256), 0, stream, gp, deg6);
    hipLaunchKernelGGL(scan6_kernel, dim3(6), dim3(256), 0, stream, deg6, rp6, cursor6);
    hipLaunchKernelGGL(scatter6_kernel, dim3((E + 255) / 256, 6), dim3(256), 0, stream,
                       gp, cursor6, csr_src6, csr_sim6);

    // ---- weights -> bf16 ----
    hipLaunchKernelGGL(wcvt_kernel, dim3(16, 8, 3), dim3(256), 0, stream, adapt_w, adapt_wt, 512, 256);
    hipLaunchKernelGGL(wcvt_qkv_kernel, dim3(8, 8, 18), dim3(256), 0, stream, q_w, k_w, v_w, W3);
    hipLaunchKernelGGL(wcvt_kernel, dim3(8, 8, 6), dim3(256), 0, stream, a_w, a_wt, 256, 256);
    hipLaunchKernelGGL(wcvt_split_kernel, dim3(16, 16), dim3(256), 0, stream, head_w, hw_hi, hw_lo, 512, 512);
    hipLaunchKernelGGL(bias_concat_kernel, dim3(18), dim3(256), 0, stream, q_b, k_b, v_b, bias768);

    // ---- adapt (all 3 types in one dispatch) ----
    Ptr3f fa; fa.p[0] = feat[0]; fa.p[1] = feat[1]; fa.p[2] = feat[2];
    hipLaunchKernelGGL(adapt_gemm3, dim3(2, 157, 3), dim3(256), 0, stream, fa, adapt_wt, adapt_b, hb);

    for (int l = 0; l < 2; ++l) {
        hipLaunchKernelGGL(qkv_gemm3, dim3(6, 157, 3), dim3(256), 0, stream,
                           hb, W3 + (size_t)l * 3 * 768 * 256, bias768 + (size_t)l * 3 * 768, qkvb);
        hipLaunchKernelGGL(attn_fused_kernel, dim3(5000, 3), dim3(256), 0, stream,
                           qkvb, rp6, csr_src6, csr_sim6, e_w + l, e_b + l, aggb);
        hipLaunchKernelGGL(a_gemm3, dim3(2, 157, 3), dim3(256), 0, stream,
                           aggb, a_wt + (size_t)l * 3 * 65536, a_b + (size_t)l * 3 * 256,
                           skip + l * 3, hb);
    }

    hipMemsetAsync(csum, 0, 256 * sizeof(float), stream);
    hipLaunchKernelGGL(colsum_kernel, dim3(128), dim3(256), 0, stream, hb, csum, NI);
    hipLaunchKernelGGL(head_kernel, dim3(1), dim3(512), 0, stream,
                       csum, (float)NI, pred_w, pred_b, head1_w, head1_b, head_w, head_b, cvec);

    // out = feats[0] @ head_w + cvec  (split-bf16 MFMA; grid-swapped so N-tiles share A)
    hipLaunchKernelGGL(mfma_gemm_split, dim3(4, 157), dim3(256), 0, stream,
                       feat[0], hw_hi, hw_lo, cvec, (float*)d_out, NI, 512, 512);
}

// Round 6
// 590.283 us; speedup vs baseline: 5.3495x; 1.0278x over previous
//
#include <hip/hip_runtime.h>
#include <hip/hip_bf16.h>
#include <math.h>

typedef short v8s __attribute__((ext_vector_type(8)));
typedef float v4f __attribute__((ext_vector_type(4)));
typedef float v2f __attribute__((ext_vector_type(2)));
typedef unsigned short u16x4 __attribute__((ext_vector_type(4)));

__device__ __forceinline__ unsigned short f2bf(float f) {
    unsigned int u = __float_as_uint(f);
    u += 0x7fff + ((u >> 16) & 1);   // round-to-nearest-even
    return (unsigned short)(u >> 16);
}
__device__ __forceinline__ float bf2f(unsigned short h) {
    return __uint_as_float(((unsigned int)h) << 16);
}
__device__ __forceinline__ void split2(float f, unsigned short& h, unsigned short& l) {
    h = f2bf(f);
    float r = f - bf2f(h);      // exact
    l = f2bf(r);
}
__device__ __forceinline__ unsigned char f2fp8(float f) {
    int e = __builtin_amdgcn_cvt_pk_fp8_f32(f, f, 0, false);
    return (unsigned char)(e & 0xff);
}

struct GraphPtrs { const int* dst[6]; const int* src[6]; const float* sim[6]; };
struct Ptr3f { const float* p[3]; };

// ---------------- weight transpose + convert: W[K][N] fp32 -> Wt[N][K] bf16 ----------------
__global__ __launch_bounds__(256)
void wcvt_kernel(const float* __restrict__ W, unsigned short* __restrict__ Wt, int K, int N)
{
    __shared__ float tile[32][33];
    const int b = blockIdx.z;
    const float* Wb = W + (size_t)b * K * N;
    unsigned short* Wtb = Wt + (size_t)b * K * N;
    const int k0 = blockIdx.x * 32, n0 = blockIdx.y * 32;
    const int x = threadIdx.x & 31, y = threadIdx.x >> 5;
    #pragma unroll
    for (int j = 0; j < 4; ++j)
        tile[y + 8 * j][x] = Wb[(size_t)(k0 + y + 8 * j) * N + n0 + x];
    __syncthreads();
    #pragma unroll
    for (int j = 0; j < 4; ++j)
        Wtb[(size_t)(n0 + y + 8 * j) * K + k0 + x] = f2bf(tile[x][y + 8 * j]);
}

// q/k/v weights -> W3[(l,t)][768][256] (rows 0-255 q, 256-511 k, 512-767 v)
__global__ __launch_bounds__(256)
void wcvt_qkv_kernel(const float* __restrict__ qw, const float* __restrict__ kw,
                     const float* __restrict__ vw, unsigned short* __restrict__ W3)
{
    __shared__ float tile[32][33];
    const int z = blockIdx.z, lt = z / 3, sec = z - lt * 3;
    const float* src = (sec == 0 ? qw : sec == 1 ? kw : vw) + (size_t)lt * 65536;
    unsigned short* dst = W3 + ((size_t)lt * 768 + sec * 256) * 256;
    const int k0 = blockIdx.x * 32, n0 = blockIdx.y * 32;
    const int x = threadIdx.x & 31, y = threadIdx.x >> 5;
    #pragma unroll
    for (int j = 0; j < 4; ++j)
        tile[y + 8 * j][x] = src[(size_t)(k0 + y + 8 * j) * 256 + n0 + x];
    __syncthreads();
    #pragma unroll
    for (int j = 0; j < 4; ++j)
        dst[(size_t)(n0 + y + 8 * j) * 256 + k0 + x] = f2bf(tile[x][y + 8 * j]);
}

// hi/lo split transpose for the final head GEMM
__global__ __launch_bounds__(256)
void wcvt_split_kernel(const float* __restrict__ W, unsigned short* __restrict__ Whi,
                       unsigned short* __restrict__ Wlo, int K, int N)
{
    __shared__ float tile[32][33];
    const int k0 = blockIdx.x * 32, n0 = blockIdx.y * 32;
    const int x = threadIdx.x & 31, y = threadIdx.x >> 5;
    #pragma unroll
    for (int j = 0; j < 4; ++j)
        tile[y + 8 * j][x] = W[(size_t)(k0 + y + 8 * j) * N + n0 + x];
    __syncthreads();
    #pragma unroll
    for (int j = 0; j < 4; ++j) {
        unsigned short h, l;
        split2(tile[x][y + 8 * j], h, l);
        size_t idx = (size_t)(n0 + y + 8 * j) * K + k0 + x;
        Whi[idx] = h; Wlo[idx] = l;
    }
}

// bias768[lt][768] = concat(q_b[lt], k_b[lt], v_b[lt])
__global__ void bias_concat_kernel(const float* __restrict__ qb, const float* __restrict__ kb,
                                   const float* __restrict__ vb, float* __restrict__ out)
{
    int i = blockIdx.x * 256 + threadIdx.x;
    if (i < 6 * 768) {
        int lt = i / 768, c = i - lt * 768;
        int sec = c >> 8, cc = c & 255;
        const float* s = sec == 0 ? qb : sec == 1 ? kb : vb;
        out[i] = s[lt * 256 + cc];
    }
}

// ---------------- CSR build (all 6 etypes fused) ----------------
__global__ void hist6_kernel(GraphPtrs gp, int* __restrict__ deg6)
{
    constexpr int doff[6] = {0, 10000, 30000, 35000, 55000, 60000};
    const int ei = blockIdx.y;
    int e = blockIdx.x * 256 + threadIdx.x;
    if (e < 100000) atomicAdd(&deg6[doff[ei] + gp.dst[ei][e]], 1);
}

__global__ __launch_bounds__(256)
void scan6_kernel(const int* __restrict__ deg6, int* __restrict__ rp6, int* __restrict__ cursor6)
{
    constexpr int ndv[6]   = {10000, 20000, 5000, 20000, 5000, 10000};
    constexpr int doff[6]  = {0, 10000, 30000, 35000, 55000, 60000};
    constexpr int rpoff[6] = {0, 10001, 30002, 35003, 55004, 60005};
    const int b = blockIdx.x;
    const int nd = ndv[b];
    const int* deg = deg6 + doff[b];
    int* rowptr = rp6 + rpoff[b];
    int* cursor = cursor6 + doff[b];
    const int t = threadIdx.x, lane = t & 63, w = t >> 6;
    __shared__ int wsum[4];
    int carry = 0;
    for (int base = 0; base < nd; base += 1024) {
        int i0 = base + t * 4;
        int x0 = 0, x1 = 0, x2 = 0, x3 = 0;
        if (i0 + 3 < nd) {
            int4 v = *(const int4*)(deg + i0);
            x0 = v.x; x1 = v.y; x2 = v.z; x3 = v.w;
        } else {
            if (i0 < nd) x0 = deg[i0];
            if (i0 + 1 < nd) x1 = deg[i0 + 1];
            if (i0 + 2 < nd) x2 = deg[i0 + 2];
            if (i0 + 3 < nd) x3 = deg[i0 + 3];
        }
        int s1 = x0 + x1, s2 = s1 + x2, tot = s2 + x3;
        int inc = tot;
        #pragma unroll
        for (int o = 1; o < 64; o <<= 1) {
            int y = __shfl_up(inc, o, 64);
            if (lane >= o) inc += y;
        }
        if (lane == 63) wsum[w] = inc;
        __syncthreads();
        int woff = 0;
        #pragma unroll
        for (int ww = 0; ww < 4; ++ww) if (ww < w) woff += wsum[ww];
        int ebase = carry + woff + inc - tot;
        if (i0 < nd)     { rowptr[i0] = ebase;          cursor[i0] = ebase; }
        if (i0 + 1 < nd) { rowptr[i0 + 1] = ebase + x0; cursor[i0 + 1] = ebase + x0; }
        if (i0 + 2 < nd) { rowptr[i0 + 2] = ebase + s1; cursor[i0 + 2] = ebase + s1; }
        if (i0 + 3 < nd) { rowptr[i0 + 3] = ebase + s2; cursor[i0 + 3] = ebase + s2; }
        carry += wsum[0] + wsum[1] + wsum[2] + wsum[3];
        __syncthreads();
    }
    if (t == 0) rowptr[nd] = carry;
}

__global__ void scatter6_kernel(GraphPtrs gp, int* __restrict__ cursor6,
                                int* __restrict__ csr_src6, float* __restrict__ csr_sim6)
{
    constexpr int doff[6] = {0, 10000, 30000, 35000, 55000, 60000};
    const int ei = blockIdx.y;
    int e = blockIdx.x * 256 + threadIdx.x;
    if (e < 100000) {
        int j = atomicAdd(&cursor6[doff[ei] + gp.dst[ei][e]], 1);
        csr_src6[(size_t)ei * 100000 + j] = gp.src[ei][e];
        csr_sim6[(size_t)ei * 100000 + j] = gp.sim[ei][e];
    }
}

// ---------------- MFMA GEMM core, fp32 A (converted on the fly) ----------------
__device__ __forceinline__ void gemm_core(const float* __restrict__ A,
    const unsigned short* __restrict__ Wt, int M, int K, int bm, int bn,
    unsigned short* __restrict__ As, unsigned short* __restrict__ Bs, v4f acc[4][4])
{
    const int tid = threadIdx.x;
    const int sr = tid >> 1, sc = (tid & 1) * 16;
    const int arow = bm + sr;
    const bool aok = arow < M;
    const float* ap = A + (size_t)arow * K + sc;
    const unsigned short* bp = Wt + (size_t)(bn + sr) * K + sc;
    const int lane = tid & 63, w = tid >> 6, wr = w >> 1, wc = w & 1;
    const int l16 = lane & 15, lg = lane >> 4;
    const int abase = (wr * 64 + l16) * 32 + lg * 8;
    const int bbase = (wc * 64 + l16) * 32 + lg * 8;

    for (int k0 = 0; k0 < K; k0 += 32) {
        float4 a0 = {0,0,0,0}, a1 = a0, a2 = a0, a3 = a0;
        if (aok) {
            a0 = *(const float4*)(ap + k0);
            a1 = *(const float4*)(ap + k0 + 4);
            a2 = *(const float4*)(ap + k0 + 8);
            a3 = *(const float4*)(ap + k0 + 12);
        }
        uint4 b0 = *(const uint4*)(bp + k0);
        uint4 b1 = *(const uint4*)(bp + k0 + 8);

        if (k0) __syncthreads();

        uint4 w0, w1;
        w0.x = (unsigned int)f2bf(a0.x) | ((unsigned int)f2bf(a0.y) << 16);
        w0.y = (unsigned int)f2bf(a0.z) | ((unsigned int)f2bf(a0.w) << 16);
        w0.z = (unsigned int)f2bf(a1.x) | ((unsigned int)f2bf(a1.y) << 16);
        w0.w = (unsigned int)f2bf(a1.z) | ((unsigned int)f2bf(a1.w) << 16);
        w1.x = (unsigned int)f2bf(a2.x) | ((unsigned int)f2bf(a2.y) << 16);
        w1.y = (unsigned int)f2bf(a2.z) | ((unsigned int)f2bf(a2.w) << 16);
        w1.z = (unsigned int)f2bf(a3.x) | ((unsigned int)f2bf(a3.y) << 16);
        w1.w = (unsigned int)f2bf(a3.z) | ((unsigned int)f2bf(a3.w) << 16);
        *(uint4*)&As[sr * 32 + sc]     = w0;
        *(uint4*)&As[sr * 32 + sc + 8] = w1;
        *(uint4*)&Bs[sr * 32 + sc]     = b0;
        *(uint4*)&Bs[sr * 32 + sc + 8] = b1;
        __syncthreads();

        v8s af[4], bfr[4];
        #pragma unroll
        for (int f = 0; f < 4; ++f) af[f] = *(const v8s*)&As[abase + f * 512];
        #pragma unroll
        for (int f = 0; f < 4; ++f) bfr[f] = *(const v8s*)&Bs[bbase + f * 512];
        #pragma unroll
        for (int i = 0; i < 4; ++i)
            #pragma unroll
            for (int j = 0; j < 4; ++j)
                acc[i][j] = __builtin_amdgcn_mfma_f32_16x16x32_bf16(af[i], bfr[j], acc[i][j], 0, 0, 0);
    }
}

// ---------------- MFMA GEMM core, bf16 A (no conversion in staging) ----------------
__device__ __forceinline__ void gemm_core_bf(const unsigned short* __restrict__ A,
    const unsigned short* __restrict__ Wt, int M, int K, int bm, int bn,
    unsigned short* __restrict__ As, unsigned short* __restrict__ Bs, v4f acc[4][4])
{
    const int tid = threadIdx.x;
    const int sr = tid >> 1, sc = (tid & 1) * 16;
    const int arow = bm + sr;
    const bool aok = arow < M;
    const unsigned short* ap = A + (size_t)arow * K + sc;
    const unsigned short* bp = Wt + (size_t)(bn + sr) * K + sc;
    const int lane = tid & 63, w = tid >> 6, wr = w >> 1, wc = w & 1;
    const int l16 = lane & 15, lg = lane >> 4;
    const int abase = (wr * 64 + l16) * 32 + lg * 8;
    const int bbase = (wc * 64 + l16) * 32 + lg * 8;

    for (int k0 = 0; k0 < K; k0 += 32) {
        uint4 a0 = {0,0,0,0}, a1 = a0;
        if (aok) {
            a0 = *(const uint4*)(ap + k0);
            a1 = *(const uint4*)(ap + k0 + 8);
        }
        uint4 b0 = *(const uint4*)(bp + k0);
        uint4 b1 = *(const uint4*)(bp + k0 + 8);

        if (k0) __syncthreads();

        *(uint4*)&As[sr * 32 + sc]     = a0;
        *(uint4*)&As[sr * 32 + sc + 8] = a1;
        *(uint4*)&Bs[sr * 32 + sc]     = b0;
        *(uint4*)&Bs[sr * 32 + sc + 8] = b1;
        __syncthreads();

        v8s af[4], bfr[4];
        #pragma unroll
        for (int f = 0; f < 4; ++f) af[f] = *(const v8s*)&As[abase + f * 512];
        #pragma unroll
        for (int f = 0; f < 4; ++f) bfr[f] = *(const v8s*)&Bs[bbase + f * 512];
        #pragma unroll
        for (int i = 0; i < 4; ++i)
            #pragma unroll
            for (int j = 0; j < 4; ++j)
                acc[i][j] = __builtin_amdgcn_mfma_f32_16x16x32_bf16(af[i], bfr[j], acc[i][j], 0, 0, 0);
    }
}

// ---- adapt: h[t] = feats[t] @ adapt_w[t] + adapt_b[t]  (3 types fused via z) ----
__global__ __launch_bounds__(256)
void adapt_gemm3(Ptr3f A3, const unsigned short* __restrict__ Wt3,
                 const float* __restrict__ bias3, float* __restrict__ hb,
                 unsigned short* __restrict__ hbf)
{
    constexpr int Ms[3] = {20000, 10000, 5000};
    constexpr size_t hoff[3] = {0, 20000ull * 256, 30000ull * 256};
    const int z = blockIdx.z;
    const int M = Ms[z];
    const int bm = blockIdx.y * 128, bn = blockIdx.x * 128;
    if (bm >= M) return;
    __shared__ unsigned short As[128 * 32], Bs[128 * 32];
    v4f acc[4][4] = {};
    gemm_core(A3.p[z], Wt3 + (size_t)z * 256 * 512, M, 512, bm, bn, As, Bs, acc);

    const int lane = threadIdx.x & 63, w = threadIdx.x >> 6;
    const int wr = w >> 1, wc = w & 1, l16 = lane & 15, lg = lane >> 4;
    const int row0 = bm + wr * 64, col0 = bn + wc * 64;
    const float* bias = bias3 + z * 256;
    float* C = hb + hoff[z];
    unsigned short* Cb = hbf + hoff[z];
    float bv[4];
    #pragma unroll
    for (int fn = 0; fn < 4; ++fn) bv[fn] = bias[col0 + fn * 16 + l16];
    #pragma unroll
    for (int fm = 0; fm < 4; ++fm)
        #pragma unroll
        for (int i = 0; i < 4; ++i) {
            int gm = row0 + fm * 16 + lg * 4 + i;
            if (gm >= M) continue;
            #pragma unroll
            for (int fn = 0; fn < 4; ++fn) {
                float val = acc[fm][fn][i] + bv[fn];
                size_t idx = (size_t)gm * 256 + col0 + fn * 16 + l16;
                C[idx] = val;
                Cb[idx] = f2bf(val);
            }
        }
}

// ---- qkv: row layout (1024 B/node): q 256xbf16 | kv 512B lane-interleaved fp8 ----
// kv byte (within section) for k[j]: 8*(j>>2)+(j&3); for v[j]: 8*(j>>2)+4+(j&3)
__global__ __launch_bounds__(256)
void qkv_gemm3(const unsigned short* __restrict__ hbf, const unsigned short* __restrict__ W3l,
               const float* __restrict__ bias768l, unsigned char* __restrict__ qkvb)
{
    constexpr int Ms[3] = {20000, 10000, 5000};
    constexpr size_t hoff[3] = {0, 20000ull * 256, 30000ull * 256};
    constexpr size_t qoffB[3] = {0, 20000ull * 1024, 30000ull * 1024};
    const int z = blockIdx.z;
    const int M = Ms[z];
    const int bm = blockIdx.y * 128, bn = blockIdx.x * 128;
    if (bm >= M) return;
    __shared__ unsigned short As[128 * 32], Bs[128 * 32];
    v4f acc[4][4] = {};
    gemm_core_bf(hbf + hoff[z], W3l + (size_t)z * 768 * 256, M, 256, bm, bn, As, Bs, acc);

    const int lane = threadIdx.x & 63, w = threadIdx.x >> 6;
    const int wr = w >> 1, wc = w & 1, l16 = lane & 15, lg = lane >> 4;
    const int row0 = bm + wr * 64, col0 = bn + wc * 64;
    const float* bias = bias768l + z * 768;
    unsigned char* base = qkvb + qoffB[z];
    float bv[4];
    #pragma unroll
    for (int fn = 0; fn < 4; ++fn) bv[fn] = bias[col0 + fn * 16 + l16];
    #pragma unroll
    for (int fm = 0; fm < 4; ++fm)
        #pragma unroll
        for (int i = 0; i < 4; ++i) {
            int gm = row0 + fm * 16 + lg * 4 + i;
            if (gm >= M) continue;
            #pragma unroll
            for (int fn = 0; fn < 4; ++fn) {
                int c = col0 + fn * 16 + l16;
                float val = acc[fm][fn][i] + bv[fn];
                unsigned char* rowp = base + (size_t)gm * 1024;
                if (c < 256) {
                    *(unsigned short*)(rowp + 2 * c) = f2bf(val);
                } else if (c < 512) {
                    int j = c - 256;
                    rowp[512 + 8 * (j >> 2) + (j & 3)] = f2fp8(val);
                } else {
                    int j = c - 512;
                    rowp[512 + 8 * (j >> 2) + 4 + (j & 3)] = f2fp8(val);
                }
            }
        }
}

// ---- a: h[t] = blend(0.5*agg[t]@a_w[l,t] + a_b[l,t], h[t])  (3 types fused) ----
__global__ __launch_bounds__(256)
void a_gemm3(const unsigned short* __restrict__ aggbf, const unsigned short* __restrict__ Wtl,
             const float* __restrict__ biasl, const float* __restrict__ skipl,
             float* __restrict__ hb, unsigned short* __restrict__ hbf)
{
    constexpr int Ms[3] = {20000, 10000, 5000};
    constexpr size_t hoff[3] = {0, 20000ull * 256, 30000ull * 256};
    const int z = blockIdx.z;
    const int M = Ms[z];
    const int bm = blockIdx.y * 128, bn = blockIdx.x * 128;
    if (bm >= M) return;
    __shared__ unsigned short As[128 * 32], Bs[128 * 32];
    v4f acc[4][4] = {};
    gemm_core_bf(aggbf + hoff[z], Wtl + (size_t)z * 65536, M, 256, bm, bn, As, Bs, acc);

    const int lane = threadIdx.x & 63, w = threadIdx.x >> 6;
    const int wr = w >> 1, wc = w & 1, l16 = lane & 15, lg = lane >> 4;
    const int row0 = bm + wr * 64, col0 = bn + wc * 64;
    const float* bias = biasl + z * 256;
    float* C = hb + hoff[z];
    unsigned short* Cb = hbf + hoff[z];
    float sv = skipl[z];
    float alpha = 1.0f / (1.0f + expf(-sv));
    float beta = 1.0f - alpha;
    float bv[4];
    #pragma unroll
    for (int fn = 0; fn < 4; ++fn) bv[fn] = bias[col0 + fn * 16 + l16];
    #pragma unroll
    for (int fm = 0; fm < 4; ++fm)
        #pragma unroll
        for (int i = 0; i < 4; ++i) {
            int gm = row0 + fm * 16 + lg * 4 + i;
            if (gm >= M) continue;
            #pragma unroll
            for (int fn = 0; fn < 4; ++fn) {
                size_t idx = (size_t)gm * 256 + col0 + fn * 16 + l16;
                float val = acc[fm][fn][i] * 0.5f + bv[fn];
                val = alpha * val + beta * C[idx];
                C[idx] = val;
                Cb[idx] = f2bf(val);
            }
        }
}

// ---------------- split-precision bf16 MFMA GEMM (final head GEMM) ----------------
__global__ __launch_bounds__(256)
void mfma_gemm_split(const float* __restrict__ A, const unsigned short* __restrict__ Whi,
                     const unsigned short* __restrict__ Wlo, const float* __restrict__ bias,
                     float* __restrict__ C, int M, int N, int K)
{
    __shared__ unsigned short Ah[128 * 32], Al[128 * 32];
    __shared__ unsigned short Bh[128 * 32], Bl[128 * 32];
    const int bm = blockIdx.y * 128, bn = blockIdx.x * 128;
    if (bm >= M) return;
    const int tid = threadIdx.x;
    const int lane = tid & 63, w = tid >> 6, wr = w >> 1, wc = w & 1;
    const int l16 = lane & 15, lg = lane >> 4;

    v4f acc[4][4] = {};

    const int sr = tid >> 1, sc = (tid & 1) * 16;
    const int arow = bm + sr;
    const bool aok = arow < M;
    const float* ap = A + (size_t)arow * K + sc;
    const unsigned short* bhp = Whi + (size_t)(bn + sr) * K + sc;
    const unsigned short* blp = Wlo + (size_t)(bn + sr) * K + sc;

    const int abase = (wr * 64 + l16) * 32 + lg * 8;
    const int bbase = (wc * 64 + l16) * 32 + lg * 8;

    for (int k0 = 0; k0 < K; k0 += 32) {
        float av[16];
        if (aok) {
            *(float4*)&av[0]  = *(const float4*)(ap + k0);
            *(float4*)&av[4]  = *(const float4*)(ap + k0 + 4);
            *(float4*)&av[8]  = *(const float4*)(ap + k0 + 8);
            *(float4*)&av[12] = *(const float4*)(ap + k0 + 12);
        } else {
            #pragma unroll
            for (int u = 0; u < 16; ++u) av[u] = 0.0f;
        }
        uint4 bh0 = *(const uint4*)(bhp + k0);
        uint4 bh1 = *(const uint4*)(bhp + k0 + 8);
        uint4 bl0 = *(const uint4*)(blp + k0);
        uint4 bl1 = *(const uint4*)(blp + k0 + 8);

        if (k0) __syncthreads();

        unsigned int hw[8], lw[8];
        #pragma unroll
        for (int u = 0; u < 8; ++u) {
            unsigned short h0, l0, h1, l1;
            split2(av[2 * u], h0, l0);
            split2(av[2 * u + 1], h1, l1);
            hw[u] = (unsigned int)h0 | ((unsigned int)h1 << 16);
            lw[u] = (unsigned int)l0 | ((unsigned int)l1 << 16);
        }
        *(uint4*)&Ah[sr * 32 + sc]     = *(uint4*)&hw[0];
        *(uint4*)&Ah[sr * 32 + sc + 8] = *(uint4*)&hw[4];
        *(uint4*)&Al[sr * 32 + sc]     = *(uint4*)&lw[0];
        *(uint4*)&Al[sr * 32 + sc + 8] = *(uint4*)&lw[4];
        *(uint4*)&Bh[sr * 32 + sc]     = bh0;
        *(uint4*)&Bh[sr * 32 + sc + 8] = bh1;
        *(uint4*)&Bl[sr * 32 + sc]     = bl0;
        *(uint4*)&Bl[sr * 32 + sc + 8] = bl1;
        __syncthreads();

        v8s ah[4], al[4], bh[4], bl[4];
        #pragma unroll
        for (int f = 0; f < 4; ++f) {
            ah[f] = *(const v8s*)&Ah[abase + f * 512];
            al[f] = *(const v8s*)&Al[abase + f * 512];
            bh[f] = *(const v8s*)&Bh[bbase + f * 512];
            bl[f] = *(const v8s*)&Bl[bbase + f * 512];
        }
        #pragma unroll
        for (int i = 0; i < 4; ++i)
            #pragma unroll
            for (int j = 0; j < 4; ++j) {
                acc[i][j] = __builtin_amdgcn_mfma_f32_16x16x32_bf16(ah[i], bh[j], acc[i][j], 0, 0, 0);
                acc[i][j] = __builtin_amdgcn_mfma_f32_16x16x32_bf16(ah[i], bl[j], acc[i][j], 0, 0, 0);
                acc[i][j] = __builtin_amdgcn_mfma_f32_16x16x32_bf16(al[i], bh[j], acc[i][j], 0, 0, 0);
            }
    }

    const int row0 = bm + wr * 64, col0 = bn + wc * 64;
    float bv[4];
    #pragma unroll
    for (int fn = 0; fn < 4; ++fn) bv[fn] = bias[col0 + fn * 16 + l16];
    #pragma unroll
    for (int fm = 0; fm < 4; ++fm)
        #pragma unroll
        for (int i = 0; i < 4; ++i) {
            int gm = row0 + fm * 16 + lg * 4 + i;
            if (gm >= M) continue;
            #pragma unroll
            for (int fn = 0; fn < 4; ++fn)
                C[(size_t)gm * N + col0 + fn * 16 + l16] = acc[fm][fn][i] + bv[fn];
        }
}

// ---------------- fused attention: fp8 k/v, one 8B/lane load per edge ----------------
__global__ __launch_bounds__(256)
void attn_fused_kernel(const unsigned char* __restrict__ qkvb,
                       const int* __restrict__ rp6, const int* __restrict__ csr_src6,
                       const float* __restrict__ csr_sim6,
                       const float* __restrict__ ewp, const float* __restrict__ ebp,
                       unsigned short* __restrict__ aggbf)
{
    constexpr int ndd[3] = {20000, 10000, 5000};
    constexpr size_t qoffB[3] = {0, 20000ull * 1024, 30000ull * 1024};
    constexpr size_t aoffE[3] = {0, 20000ull * 256, 30000ull * 256};
    constexpr int rpoff[6] = {0, 10001, 30002, 35003, 55004, 60005};
    constexpr int eA[3] = {1, 0, 2}, eB[3] = {3, 5, 4};      // incoming etypes per dst type
    constexpr int sA[3] = {1, 0, 0}, sB[3] = {2, 2, 1};      // their src node types

    const int z = blockIdx.y;
    const int d = blockIdx.x * 4 + (threadIdx.x >> 6);
    if (d >= ndd[z]) return;
    const int t = threadIdx.x & 63;
    const float ewv = ewp[0], ebv = ebp[0];

    u16x4 q4 = *(const u16x4*)(qkvb + qoffB[z] + (size_t)d * 1024 + 8 * t);
    const float qx0 = bf2f(q4[0]), qx1 = bf2f(q4[1]), qx2 = bf2f(q4[2]), qx3 = bf2f(q4[3]);

    float4 res = {0.f, 0.f, 0.f, 0.f};
    #pragma unroll
    for (int r = 0; r < 2; ++r) {
        const int ei = r == 0 ? eA[z] : eB[z];
        const int stp = r == 0 ? sA[z] : sB[z];
        const int* rowptr = rp6 + rpoff[ei];
        const int* csrc = csr_src6 + (size_t)ei * 100000;
        const float* csim = csr_sim6 + (size_t)ei * 100000;
        const unsigned char* kvsec = qkvb + qoffB[stp] + 512 + 8 * t;  // per-lane base
        const int beg = rowptr[d], end = rowptr[d + 1];
        const int n = end - beg;

        float m = -INFINITY, s = 0.0f;
        float4 acc = {0.f, 0.f, 0.f, 0.f};

        // 3-deep pipeline: two edges in flight
        uint2 kv0 = {0, 0}, kv1 = {0, 0};
        float sim0 = 0.0f, sim1 = 0.0f;
        if (n > 0) {
            kv0 = *(const uint2*)(kvsec + (size_t)csrc[beg] * 1024);
            sim0 = csim[beg];
        }
        if (n > 1) {
            kv1 = *(const uint2*)(kvsec + (size_t)csrc[beg + 1] * 1024);
            sim1 = csim[beg + 1];
        }
        for (int j = 0; j < n; ++j) {
            uint2 kvc = kv0; float simc = sim0;
            kv0 = kv1; sim0 = sim1;
            if (j + 2 < n) {
                kv1 = *(const uint2*)(kvsec + (size_t)csrc[beg + j + 2] * 1024);
                sim1 = csim[beg + j + 2];
            }
            v2f k01 = __builtin_amdgcn_cvt_pk_f32_fp8((int)kvc.x, false);
            v2f k23 = __builtin_amdgcn_cvt_pk_f32_fp8((int)kvc.x, true);
            float dot = qx0 * k01[0] + qx1 * k01[1] + qx2 * k23[0] + qx3 * k23[1];
            dot += __shfl_xor(dot, 1);
            dot += __shfl_xor(dot, 2);
            dot += __shfl_xor(dot, 4);
            float sc = dot * (simc * ewv + ebv) * 0.17677669529663687f;  // 1/sqrt(32)
            if (sc > m) {
                float rr = __expf(m - sc);
                s *= rr;
                acc.x *= rr; acc.y *= rr; acc.z *= rr; acc.w *= rr;
                m = sc;
            }
            float ex = __expf(sc - m);
            s += ex;
            v2f v01 = __builtin_amdgcn_cvt_pk_f32_fp8((int)kvc.y, false);
            v2f v23 = __builtin_amdgcn_cvt_pk_f32_fp8((int)kvc.y, true);
            acc.x += ex * v01[0]; acc.y += ex * v01[1];
            acc.z += ex * v23[0]; acc.w += ex * v23[1];
        }
        float inv = (n > 0) ? 1.0f / s : 0.0f;
        res.x += acc.x * inv; res.y += acc.y * inv;
        res.z += acc.z * inv; res.w += acc.w * inv;
    }
    u16x4 out;
    out[0] = f2bf(res.x); out[1] = f2bf(res.y);
    out[2] = f2bf(res.z); out[3] = f2bf(res.w);
    *(u16x4*)(aggbf + aoffE[z] + (size_t)d * 256 + 4 * t) = out;
}

__global__ void colsum_kernel(const float* __restrict__ h, float* __restrict__ out, int N)
{
    int c = threadIdx.x;
    float acc = 0.0f;
    for (int r = blockIdx.x; r < N; r += gridDim.x)
        acc += h[(size_t)r * 256 + c];
    atomicAdd(&out[c], acc);
}

__global__ __launch_bounds__(512)
void head_kernel(const float* __restrict__ colsum, float n_img,
                 const float* __restrict__ pred_w, const float* __restrict__ pred_b,
                 const float* __restrict__ head1_w, const float* __restrict__ head1_b,
                 const float* __restrict__ head_w, const float* __restrict__ head_b,
                 float* __restrict__ cvec)
{
    __shared__ float mean[256], o0[256], g[512];
    int t = threadIdx.x;
    if (t < 256) mean[t] = colsum[t] / n_img;
    __syncthreads();
    if (t < 256) {
        float acc = pred_b[t];
        for (int k = 0; k < 256; ++k) acc += mean[k] * pred_w[k * 256 + t];
        o0[t] = acc;
    }
    __syncthreads();
    {
        float acc = head1_b[t];
        for (int k = 0; k < 256; ++k) acc += o0[k] * head1_w[k * 512 + t];
        g[t] = acc;
    }
    __syncthreads();
    {
        float acc = head_b[t];
        for (int k = 0; k < 512; ++k) acc += g[k] * head_w[k * 512 + t];
        cvec[t] = acc;
    }
}

extern "C" void kernel_launch(void* const* d_in, const int* in_sizes, int n_in,
                              void* d_out, int out_size, void* d_ws, size_t ws_size,
                              hipStream_t stream)
{
    const int NI = 20000, E = 100000;

    const float* feat[3] = {(const float*)d_in[0], (const float*)d_in[1], (const float*)d_in[2]};
    const float* adapt_w = (const float*)d_in[3];
    const float* adapt_b = (const float*)d_in[4];
    const float* k_w = (const float*)d_in[5];
    const float* k_b = (const float*)d_in[6];
    const float* q_w = (const float*)d_in[7];
    const float* q_b = (const float*)d_in[8];
    const float* v_w = (const float*)d_in[9];
    const float* v_b = (const float*)d_in[10];
    const float* a_w = (const float*)d_in[11];
    const float* a_b = (const float*)d_in[12];
    const float* e_w = (const float*)d_in[13];
    const float* e_b = (const float*)d_in[14];
    const float* skip = (const float*)d_in[15];
    const float* pred_w = (const float*)d_in[16];
    const float* pred_b = (const float*)d_in[17];
    const float* head1_w = (const float*)d_in[19];
    const float* head1_b = (const float*)d_in[20];
    const float* head_w = (const float*)d_in[21];
    const float* head_b = (const float*)d_in[22];

    GraphPtrs gp;
    for (int i = 0; i < 6; ++i) {
        gp.sim[i] = (const float*)d_in[23 + i];
        gp.src[i] = (const int*)d_in[29 + 2 * i];
        gp.dst[i] = (const int*)d_in[30 + 2 * i];
    }

    float* ws = (float*)d_ws;
    size_t off = 0;
    auto alloc = [&](size_t n) { float* p = ws + off; off += (n + 3) & ~(size_t)3; return p; };
    const size_t NTOT = 35000ull * 256;
    float* hb = alloc(NTOT);
    unsigned short* hbf   = (unsigned short*)alloc(NTOT / 2);
    unsigned short* aggbf = (unsigned short*)alloc(NTOT / 2);
    unsigned char* qkvb   = (unsigned char*)alloc(35000ull * 256);   // 1024 B per node
    float* csum = alloc(256);
    float* cvec = alloc(512);
    int* deg6    = (int*)alloc(70000);
    int* cursor6 = (int*)alloc(70000);
    int* rp6     = (int*)alloc(70012);
    int* csr_src6   = (int*)alloc(600000);
    float* csr_sim6 = alloc(600000);
    unsigned short* adapt_wt = (unsigned short*)alloc(3 * 512 * 256 / 2);
    unsigned short* W3   = (unsigned short*)alloc(6ull * 768 * 256 / 2);  // [lt][768][256]
    unsigned short* a_wt = (unsigned short*)alloc(6 * 65536 / 2);
    float* bias768 = alloc(6 * 768);
    unsigned short* hw_hi = (unsigned short*)alloc(512 * 512 / 2);
    unsigned short* hw_lo = (unsigned short*)alloc(512 * 512 / 2);

    // ---- CSR build: 4 dispatches for all 6 etypes ----
    hipMemsetAsync(deg6, 0, 70000 * sizeof(int), stream);
    hipLaunchKernelGGL(hist6_kernel, dim3((E + 255) / 256, 6), dim3(256), 0, stream, gp, deg6);
    hipLaunchKernelGGL(scan6_kernel, dim3(6), dim3(256), 0, stream, deg6, rp6, cursor6);
    hipLaunchKernelGGL(scatter6_kernel, dim3((E + 255) / 256, 6), dim3(256), 0, stream,
                       gp, cursor6, csr_src6, csr_sim6);

    // ---- weights -> bf16 ----
    hipLaunchKernelGGL(wcvt_kernel, dim3(16, 8, 3), dim3(256), 0, stream, adapt_w, adapt_wt, 512, 256);
    hipLaunchKernelGGL(wcvt_qkv_kernel, dim3(8, 8, 18), dim3(256), 0, stream, q_w, k_w, v_w, W3);
    hipLaunchKernelGGL(wcvt_kernel, dim3(8, 8, 6), dim3(256), 0, stream, a_w, a_wt, 256, 256);
    hipLaunchKernelGGL(wcvt_split_kernel, dim3(16, 16), dim3(256), 0, stream, head_w, hw_hi, hw_lo, 512, 512);
    hipLaunchKernelGGL(bias_concat_kernel, dim3(18), dim3(256), 0, stream, q_b, k_b, v_b, bias768);

    // ---- adapt (all 3 types in one dispatch) ----
    Ptr3f fa; fa.p[0] = feat[0]; fa.p[1] = feat[1]; fa.p[2] = feat[2];
    hipLaunchKernelGGL(adapt_gemm3, dim3(2, 157, 3), dim3(256), 0, stream, fa, adapt_wt, adapt_b, hb, hbf);

    for (int l = 0; l < 2; ++l) {
        hipLaunchKernelGGL(qkv_gemm3, dim3(6, 157, 3), dim3(256), 0, stream,
                           hbf, W3 + (size_t)l * 3 * 768 * 256, bias768 + (size_t)l * 3 * 768, qkvb);
        hipLaunchKernelGGL(attn_fused_kernel, dim3(5000, 3), dim3(256), 0, stream,
                           qkvb, rp6, csr_src6, csr_sim6, e_w + l, e_b + l, aggbf);
        hipLaunchKernelGGL(a_gemm3, dim3(2, 157, 3), dim3(256), 0, stream,
                           aggbf, a_wt + (size_t)l * 3 * 65536, a_b + (size_t)l * 3 * 256,
                           skip + l * 3, hb, hbf);
    }

    hipMemsetAsync(csum, 0, 256 * sizeof(float), stream);
    hipLaunchKernelGGL(colsum_kernel, dim3(128), dim3(256), 0, stream, hb, csum, NI);
    hipLaunchKernelGGL(head_kernel, dim3(1), dim3(512), 0, stream,
                       csum, (float)NI, pred_w, pred_b, head1_w, head1_b, head_w, head_b, cvec);

    // out = feats[0] @ head_w + cvec  (split-bf16 MFMA; grid-swapped so N-tiles share A)
    hipLaunchKernelGGL(mfma_gemm_split, dim3(4, 157), dim3(256), 0, stream,
                       feat[0], hw_hi, hw_lo, cvec, (float*)d_out, NI, 512, 512);
}